// Round 11
// baseline (122.715 us; speedup 1.0000x reference)
//
#include <hip/hip_runtime.h>
#include <math.h>

// ---------------------------------------------------------------------------
// PatchedCausalSelfAttention  B=4 S=2048 D=768 DC=384 H=12 HD=32
//   prep_all : casts + transposes                        (1 launch)
//   gemm_prep: WcT[1152][768], WbpT[768][384], bc        (1 launch)
//   gemm_qkvt: QKbuf[8192][768], VT[384][8320-pad]       (1 launch)
//   attn     : ctx[8192][384] flash-causal. 4-wave blocks, 128 q-rows/block.
//   gemm_out : out[8192][768] fp32
// R1-R9 model: staged-GEMM time ~= total gload_lds bytes / ~9-11 B/cy/CU,
// invariant to sync structure, occupancy, buffer depth (R9), tile SHAPE at
// fixed bytes. Only unexplored lever: BYTES PER OUTPUT. This round:
// 128x256 block tile, 8 waves (512 thr), wave-tile 64x64, BK=32 depth-3 —
// stages A 8KB + B 16KB = 24KB per k-step for TWO 128^2-tile-equivalents
// (12KB/tile-eq vs 16KB) -> 25% fewer staged bytes at equal waves/CU
// (qkvt 288 blocks x 8w = 9 waves/CU, same as 576x4). LDS 72KB (3-deep),
// 2 blocks/CU. Counted vmcnt 6/3/0 (3 loads/stage). gemm_out same (192
// blocks). gemm_prep keeps the 4-wave R9 tile (tiny). attn untouched.
// XCD-chunked grouping: 9 jobs (6 QK + 3 VT) per 256-token superstrip.
// ---------------------------------------------------------------------------

typedef unsigned short u16;
typedef unsigned int   u32;

#define VLD 8320   // VT leading dimension (elements)

using short8 = __attribute__((ext_vector_type(8))) short;  // 8 bf16
using bf16x4 = __attribute__((ext_vector_type(4))) short;  // 4 bf16
using f32x4  = __attribute__((ext_vector_type(4))) float;

__device__ __forceinline__ u16 f2bf(float f) {
  u32 u = __builtin_bit_cast(u32, f);
  u = (u + 0x7fffu + ((u >> 16) & 1u)) >> 16;   // RNE
  return (u16)u;
}

__device__ __forceinline__ float b2f(u16 b) {
  return __builtin_bit_cast(float, (u32)b << 16);
}

__device__ __forceinline__ u32 cvtpk_bf16(float lo, float hi) {
  u32 d;
  asm("v_cvt_pk_bf16_f32 %0, %1, %2" : "=v"(d) : "v"(lo), "v"(hi));
  return d;
}

__device__ __forceinline__ bf16x4 pack4(const f32x4 v) {
  union { u32 u[2]; bf16x4 s; } c;
  c.u[0] = cvtpk_bf16(v[0], v[1]);
  c.u[1] = cvtpk_bf16(v[2], v[3]);
  return c.s;
}

// single-instruction 2^x (v_exp_f32). Large-negative inputs underflow to 0.
__device__ __forceinline__ float exp2v(float x) {
  return __builtin_amdgcn_exp2f(x);
}

__device__ __forceinline__ f32x4 mfma16bf(bf16x4 a, bf16x4 b, f32x4 c) {
#if __has_builtin(__builtin_amdgcn_mfma_f32_16x16x16bf16_1k)
  return __builtin_amdgcn_mfma_f32_16x16x16bf16_1k(a, b, c, 0, 0, 0);
#elif __has_builtin(__builtin_amdgcn_mfma_f32_16x16x16_bf16)
  return __builtin_amdgcn_mfma_f32_16x16x16_bf16(a, b, c, 0, 0, 0);
#else
  f32x4 d;  // non-volatile: scheduler may interleave with surrounding VALU
  asm("v_mfma_f32_16x16x16_bf16 %0, %1, %2, %3"
      : "=v"(d) : "v"(a), "v"(b), "v"(c));
  return d;
#endif
}

__device__ __forceinline__ void gload_lds16(const void* g, void* l) {
  __builtin_amdgcn_global_load_lds((__attribute__((address_space(1))) u32*)g,
                                   (__attribute__((address_space(3))) u32*)l,
                                   16, 0, 0);
}

// LDS byte offset of a pointer known to be in LDS (generic -> AS3 -> int).
__device__ __forceinline__ u32 lds_u32(const void* p) {
  return (u32)(size_t)(const __attribute__((address_space(3))) char*)p;
}

// ---------------- mega-prep: casts + transposes -----------------------------
__global__ __launch_bounds__(256) void prep_all(
    const float* __restrict__ x, const float* __restrict__ Wa,
    const float* __restrict__ Wb, const float* __restrict__ Pq,
    const float* __restrict__ Pk, const float* __restrict__ Pv,
    const float* __restrict__ Wp,
    u16* __restrict__ x_bf, u16* __restrict__ Wat_bf, u16* __restrict__ Wbk_bf,
    u16* __restrict__ PT, u16* __restrict__ WprT) {
  __shared__ float t[32][33];
  const int blk = blockIdx.x, tid = threadIdx.x;
  if (blk < 8160) {  // vectorized casts (x4 floats per thread)
    const float* src; u16* dst; int i;
    if (blk < 6144)      { src = x;  dst = x_bf;   i = blk * 256 + tid; }
    else if (blk < 7872) { src = Wa; dst = Wat_bf; i = (blk - 6144) * 256 + tid; }
    else                 { src = Wb; dst = Wbk_bf; i = (blk - 7872) * 256 + tid; }
    const float4 v = ((const float4*)src)[i];
    ((ushort4*)dst)[i] = make_ushort4(f2bf(v.x), f2bf(v.y), f2bf(v.z), f2bf(v.w));
    return;
  }
  // transpose+cast 32x32 tiles
  const float* src; u16* dst; int C, R, bx, by;
  if (blk < 8448)      { src = Pq; dst = PT;             R = 768; C = 384; int t2 = blk - 8160; bx = t2 % 12; by = t2 / 12; }
  else if (blk < 8736) { src = Pk; dst = PT + 384 * 768; R = 768; C = 384; int t2 = blk - 8448; bx = t2 % 12; by = t2 / 12; }
  else if (blk < 9024) { src = Pv; dst = PT + 768 * 768; R = 768; C = 384; int t2 = blk - 8736; bx = t2 % 12; by = t2 / 12; }
  else                 { src = Wp; dst = WprT;           R = 768; C = 768; int t2 = blk - 9024; bx = t2 % 24; by = t2 / 24; }
  const int c0 = bx * 32, r0 = by * 32, tx = tid & 31, ty = tid >> 5;
  for (int i = ty; i < 32; i += 8)
    t[i][tx] = src[(size_t)(r0 + i) * C + c0 + tx];
  __syncthreads();
  for (int i = ty; i < 32; i += 8)
    dst[(size_t)(c0 + i) * R + r0 + tx] = f2bf(t[tx][i]);
}

// ---------------- bf16 MFMA GEMM tile 128x256, 8-wave depth-3 pipeline ------
// 8 waves (2M x 4N), wave-tile 64x64, acc[4][4]. BK=32, triple-buffered:
// As 3x8KB + Bs 3x16KB = 72KB LDS. 3 loads/thread/stage -> vmcnt 6/3/0.
template<int OBF16>
__device__ __forceinline__ void gemm_tile8(
    const u16* __restrict__ A, const u16* __restrict__ BT,
    const float* __restrict__ bias, void* __restrict__ Cv,
    int K, int lda, int ldb, int ldc, int m0, int n0, int biasmode,
    u16* As, u16* Bs) {
  const int tid = threadIdx.x;            // 0..511
  const int l = tid & 63, w = tid >> 6;   // wave 0..7
  const int r = l & 15, g = l >> 4;
  const int w8 = w;                       // stage row/col block = wave id
  const u16* Ap = A + ((size_t)m0 + w8 * 16 + r) * lda + g * 8;
  const u16* Bp = BT + ((size_t)n0 + w8 * 16 + r) * ldb + g * 8;
  f32x4 acc[4][4] = {};
  const int wm = w >> 2, wn = w & 3;      // 2M x 4N wave grid
  const int nk = K >> 5;                  // 12 or 24

  const u32 abase = lds_u32(As) + (u32)(wm * 4096 + l * 16);  // 4 rowblks/wave
  const u32 bbase = lds_u32(Bs) + (u32)(wn * 4096 + l * 16);  // 4 colblks/wave

  auto stage = [&](int kt, int buf) {
    gload_lds16(Ap + kt,                     &As[buf * 4096 + (size_t)tid * 8]);
    gload_lds16(Bp + kt,                     &Bs[buf * 8192 + (size_t)tid * 8]);
    gload_lds16(Bp + kt + (size_t)128 * ldb, &Bs[buf * 8192 + 4096 + (size_t)tid * 8]);
  };

  stage(0, 0);
  stage(32, 1);
  stage(64, 2);                     // 9 loads in flight / thread
  int cur = 0;
  for (int t = 0; t < nk; ++t) {
    if (t + 2 < nk)      asm volatile("s_waitcnt vmcnt(6)" ::: "memory");
    else if (t + 1 < nk) asm volatile("s_waitcnt vmcnt(3)" ::: "memory");
    else                 asm volatile("s_waitcnt vmcnt(0)" ::: "memory");
    __builtin_amdgcn_s_barrier();   // tile t resident in buf cur (all waves)
    __builtin_amdgcn_sched_barrier(0);
    const u32 aoff = (u32)(cur * 8192);   // A buffer stride 8KB
    const u32 boff = (u32)(cur * 16384);  // B buffer stride 16KB
    short8 af[4], bfr[4];
    #pragma unroll
    for (int i = 0; i < 4; ++i) {
      asm volatile("ds_read_b128 %0, %1" : "=v"(af[i])  : "v"(abase + aoff + 1024u * i));
      asm volatile("ds_read_b128 %0, %1" : "=v"(bfr[i]) : "v"(bbase + boff + 1024u * i));
    }
    asm volatile("s_waitcnt lgkmcnt(0)" ::: "memory");
    __builtin_amdgcn_sched_barrier(0);  // rule 18: nothing hoists above the wait
    __builtin_amdgcn_s_barrier();       // all waves' reads done -> buf cur free
    __builtin_amdgcn_sched_barrier(0);
    if (t + 3 < nk) stage((t + 3) << 5, cur);  // refill freed buffer, in flight
    #pragma unroll
    for (int mi = 0; mi < 4; ++mi)
      #pragma unroll
      for (int ni = 0; ni < 4; ++ni)
        acc[mi][ni] = __builtin_amdgcn_mfma_f32_16x16x32_bf16(af[mi], bfr[ni],
                                                              acc[mi][ni], 0, 0, 0);
    cur = (cur == 2) ? 0 : cur + 1;
  }

  const int row0 = m0 + wm * 64, col0 = n0 + wn * 64;
  #pragma unroll
  for (int ni = 0; ni < 4; ++ni) {
    const int col = col0 + ni * 16 + r;
    const float bvc = (biasmode == 1) ? bias[col] : 0.f;
    #pragma unroll
    for (int mi = 0; mi < 4; ++mi)
      #pragma unroll
      for (int j = 0; j < 4; ++j) {
        const int row = row0 + mi * 16 + 4 * g + j;
        float bv = bvc;
        if (biasmode == 2) bv = bias[row];
        const float v = acc[mi][ni][j] + bv;
        if (OBF16) ((u16*)Cv)[(size_t)row * ldc + col] = f2bf(v);
        else       ((float*)Cv)[(size_t)row * ldc + col] = v;
      }
  }
}

// ---------------- bf16 MFMA GEMM tile 128x128, depth-3 (4-wave, prep only) --
template<int OBF16>
__device__ __forceinline__ void gemm_tile4(
    const u16* __restrict__ A, const u16* __restrict__ BT,
    const float* __restrict__ bias, void* __restrict__ Cv,
    int K, int lda, int ldb, int ldc, int m0, int n0, int biasmode, bool slab,
    u16* As, u16* Bs) {
  const int tid = threadIdx.x;
  const int l = tid & 63, w = tid >> 6;
  const int r = l & 15, g = l >> 4;
  const int koff = slab ? (m0 / 384) * 768 : 0;
  const u16* Ap = A + ((size_t)m0 + w * 16 + r) * lda + g * 8;
  const u16* Bp = BT + ((size_t)n0 + w * 16 + r) * ldb + koff + g * 8;
  f32x4 acc[4][4] = {};
  const int wma = (w >> 1) * 4, wnb = (w & 1) * 4;
  const int nk = K >> 5;

  const u32 abase = lds_u32(As) + (u32)(wma * 1024 + l * 16);
  const u32 bbase = lds_u32(Bs) + (u32)(wnb * 1024 + l * 16);

  auto stage = [&](int kt, int buf) {
    const int o = buf * 4096;
    gload_lds16(Ap + kt,                    &As[o + (size_t)tid * 8]);
    gload_lds16(Ap + kt + (size_t)64 * lda, &As[o + 2048 + (size_t)tid * 8]);
    gload_lds16(Bp + kt,                    &Bs[o + (size_t)tid * 8]);
    gload_lds16(Bp + kt + (size_t)64 * ldb, &Bs[o + 2048 + (size_t)tid * 8]);
  };

  stage(0, 0);
  stage(32, 1);
  stage(64, 2);
  int cur = 0;
  for (int t = 0; t < nk; ++t) {
    if (t + 2 < nk)      asm volatile("s_waitcnt vmcnt(8)" ::: "memory");
    else if (t + 1 < nk) asm volatile("s_waitcnt vmcnt(4)" ::: "memory");
    else                 asm volatile("s_waitcnt vmcnt(0)" ::: "memory");
    __builtin_amdgcn_s_barrier();
    __builtin_amdgcn_sched_barrier(0);
    const u32 off = (u32)(cur * 8192);
    short8 af[4], bfr[4];
    #pragma unroll
    for (int i = 0; i < 4; ++i) {
      asm volatile("ds_read_b128 %0, %1" : "=v"(af[i])  : "v"(abase + off + 1024u * i));
      asm volatile("ds_read_b128 %0, %1" : "=v"(bfr[i]) : "v"(bbase + off + 1024u * i));
    }
    asm volatile("s_waitcnt lgkmcnt(0)" ::: "memory");
    __builtin_amdgcn_sched_barrier(0);
    __builtin_amdgcn_s_barrier();
    __builtin_amdgcn_sched_barrier(0);
    if (t + 3 < nk) stage((t + 3) << 5, cur);
    #pragma unroll
    for (int mi = 0; mi < 4; ++mi)
      #pragma unroll
      for (int ni = 0; ni < 4; ++ni)
        acc[mi][ni] = __builtin_amdgcn_mfma_f32_16x16x32_bf16(af[mi], bfr[ni],
                                                              acc[mi][ni], 0, 0, 0);
    cur = (cur == 2) ? 0 : cur + 1;
  }

  const int row0 = m0 + (w >> 1) * 64, col0 = n0 + (w & 1) * 64;
  #pragma unroll
  for (int ni = 0; ni < 4; ++ni) {
    const int col = col0 + ni * 16 + r;
    const float bvc = (biasmode == 1) ? bias[col] : 0.f;
    #pragma unroll
    for (int mi = 0; mi < 4; ++mi)
      #pragma unroll
      for (int j = 0; j < 4; ++j) {
        const int row = row0 + mi * 16 + 4 * g + j;
        float bv = bvc;
        if (biasmode == 2) bv = bias[row];
        const float v = acc[mi][ni][j] + bv;
        if (OBF16) ((u16*)Cv)[(size_t)row * ldc + col] = f2bf(v);
        else       ((float*)Cv)[(size_t)row * ldc + col] = v;
      }
  }
}

// prep GEMMs: [0,54) WcT; [54,72) WbpT; [72,80) bc = ba(slab) . PT rows
__global__ __launch_bounds__(256, 3) void gemm_prep(
    const u16* __restrict__ PT, const u16* __restrict__ Wat,
    const u16* __restrict__ WprT, const u16* __restrict__ Wbk,
    const float* __restrict__ ba,
    u16* __restrict__ WcT, u16* __restrict__ WbpT, float* __restrict__ bc) {
  __shared__ alignas(16) u16 As[12288], Bs[12288];
  const int t = blockIdx.x;
  if (t < 54) {
    gemm_tile4<1>(PT, Wat, nullptr, WcT, 768, 768, 2304, 768,
                  (t % 9) * 128, (t / 9) * 128, 0, true, As, Bs);
  } else if (t < 72) {
    const int t2 = t - 54;
    gemm_tile4<1>(WprT, Wbk, nullptr, WbpT, 768, 768, 768, 384,
                  (t2 % 6) * 128, (t2 / 6) * 128, 0, false, As, Bs);
  } else {
    const int c = (t - 72) * 144 + threadIdx.x;
    if (threadIdx.x < 144 && c < 1152) {
      const int slab = c / 384;
      const float* bs = ba + slab * 768;
      const u16* row = PT + (size_t)c * 768;
      float s = 0.f;
      for (int jj = 0; jj < 96; ++jj) {
        const short8 v = *(const short8*)&row[jj * 8];
        #pragma unroll
        for (int e = 0; e < 8; ++e)
          s = fmaf(bs[jj * 8 + e], b2f((u16)v[e]), s);
      }
      bc[c] = s;
    }
  }
}

// main GEMMs, XCD-chunked: 9 jobs per 256-token superstrip (6 QK 128x256 +
// 3 VT 128x256 reading the same x_bf rows); xcd = t%8 round-robin.
__global__ __launch_bounds__(512, 4) void gemm_qkvt(
    const u16* __restrict__ x_bf, const u16* __restrict__ WcT,
    const float* __restrict__ bc, u16* __restrict__ QKbuf, u16* __restrict__ VTbuf) {
  __shared__ alignas(16) u16 As[12288], Bs[24576];
  const int t = blockIdx.x;                 // 288 = 8 xcd * 36
  const int w = (t & 7) * 36 + (t >> 3);    // XCD-chunked logical id
  const int S = w / 9, j = w % 9;           // 256-token superstrip, sub-job
  if (j < 6) {                              // QK: strip = S*2 + (j&1), panel j>>1
    gemm_tile8<1>(x_bf, WcT, bc, QKbuf, 768, 768, 768, 768,
                  (S * 2 + (j & 1)) * 128, (j >> 1) * 256, 1, As, Bs);
  } else {                                  // VT: row-panel j-6, token strip S
    gemm_tile8<1>(WcT + (size_t)(768 + (j - 6) * 128) * 768 - (size_t)(j - 6) * 128 * 768
                    + (size_t)0, x_bf, bc + 768, VTbuf, 768, 768, 768, VLD,
                  (j - 6) * 128, S * 256, 2, As, Bs);
  }
}

__global__ __launch_bounds__(512, 4) void gemm_out(
    const u16* __restrict__ ctx, const u16* __restrict__ WbpT,
    const float* __restrict__ bp, float* __restrict__ out) {
  __shared__ alignas(16) u16 As[12288], Bs[24576];
  const int t = blockIdx.x;                 // 192 = 8 xcd * 24
  const int w = (t & 7) * 24 + (t >> 3);    // XCD-chunked logical id
  gemm_tile8<0>(ctx, WbpT, bp, out, 384, 384, 384, 768,
                (w / 3) * 128, (w % 3) * 256, 1, As, Bs);
}

// ---------------- causal flash attention, 4-wave LDS-staged blocks ----------
// grid: 768 blocks x 256 thr (heavy chunks first, global order — R1-proven).
// Block = 128 q-rows of one (b,h); wave w owns rows [cc*128 + w*32, +32).
// K staged via global_load_lds; V staged reg->LDS issue-early/write-late
// (T14). Double-buffered: stage t+1, compute t, barrier. PV in-register.
__global__ __launch_bounds__(256, 4) void attn_kernel(
    const u16* __restrict__ QK, const u16* __restrict__ VT,
    u16* __restrict__ ctx) {
  __shared__ alignas(16) u16 Ks[2][2048];      // 4KB per buffer
  __shared__ alignas(16) u16 Vs[2][32 * 72];   // 4.5KB per buffer (padded rows)
  const int tid = threadIdx.x;
  const int w = tid >> 6, l = tid & 63;
  const int r = l & 15, g = l >> 4;
  const int idx = blockIdx.x;
  const int cc = 15 - idx / 48;                // q-chunk (128 rows), heavy first
  const int bh = idx % 48;
  const int b = bh / 12, h = bh % 12;
  const size_t tok0 = (size_t)b * 2048;
  const int q0 = cc * 128 + w * 32;            // this wave's q-strip base
  const u16* Qb = QK + (tok0 + q0) * 768 + h * 32;
  const u16* Kb = QK + tok0 * 768 + 384 + h * 32;
  const u16* Vb = VT + (size_t)(h * 32) * VLD + b * 2048;
  const float scale2 = 0.25500526474f;         // (1/sqrt(32))*log2(e)
  const float THR = 8.0f;                      // defer-max threshold (T13)
  const f32x4 fz = {0.f, 0.f, 0.f, 0.f};

  short8 qf[2];
  qf[0] = *(const short8*)&Qb[(size_t)r * 768 + 8 * g];
  qf[1] = *(const short8*)&Qb[(size_t)(16 + r) * 768 + 8 * g];

  float mrun[2] = {-3.0e38f, -3.0e38f};
  float lpart[2] = {0.f, 0.f};                 // per-lane partial row sums
  f32x4 o[2][2] = {};                          // o[di][mi]: d=16di+4g+jj, q=16mi+r
  const int ntb = 2 * (cc + 1);                // block k-tiles
  const int ntw = (q0 + 31) / 64 + 1;          // this wave's compute tiles

  // staging roles (fixed per thread; all 256 threads do K and V)
  const int krow = ((tid >> 6) << 4) + (tid & 15);   // K chunk row
  const int kcol = ((tid >> 4) & 3) * 8;             // K chunk col
  const int vd   = tid >> 3;                          // V row d (0..31)
  const int vkc  = (tid & 7) * 8;                     // V col chunk

  uint4 vreg;
  auto stageK = [&](int t, int buf) {
    gload_lds16(&Kb[(size_t)(t * 64 + krow) * 768 + kcol], &Ks[buf][(size_t)tid * 8]);
  };
  auto loadV = [&](int t) {
    vreg = *(const uint4*)&Vb[(size_t)vd * VLD + t * 64 + vkc];
  };
  auto writeV = [&](int buf) {
    *(uint4*)&Vs[buf][vd * 72 + vkc] = vreg;
  };

  loadV(0); stageK(0, 0); writeV(0);
  __syncthreads();
  int cur = 0;
  for (int t = 0; t < ntb; ++t) {
    const bool pf = (t + 1 < ntb);
    if (pf) { loadV(t + 1); stageK(t + 1, cur ^ 1); }  // issue next tile early
    if (t < ntw) {
      // K fragments (A of 16x16x32): lane holds K[k=16kj+r][hd=8g..]
      short8 kf[4];
      #pragma unroll
      for (int kj = 0; kj < 4; ++kj)
        kf[kj] = *(const short8*)&Ks[cur][((kj * 64 + l)) * 8];
      // V^T fragments (A of 16x16x16): lane holds VT[d=16di+r][k=16kj+4g..+3]
      bf16x4 vf[2][4];
      #pragma unroll
      for (int di = 0; di < 2; ++di)
        #pragma unroll
        for (int kj = 0; kj < 4; ++kj)
          vf[di][kj] = *(const bf16x4*)&Vs[cur][(16 * di + r) * 72 + kj * 16 + 4 * g];

      // S^T = K Q^T : lane holds S[k=16kj+4g+jj][q=16mi+r]  (raw)
      f32x4 s[2][4];
      __builtin_amdgcn_s_setprio(1);
      #pragma unroll
      for (int kj = 0; kj < 4; ++kj)
        #pragma unroll
        for (int mi = 0; mi < 2; ++mi)
          s[mi][kj] = __builtin_amdgcn_mfma_f32_16x16x32_bf16(kf[kj], qf[mi], fz, 0, 0, 0);
      __builtin_amdgcn_s_setprio(0);

      if (t == ntw - 1) {  // only the diagonal tile needs masking
        #pragma unroll
        for (int mi = 0; mi < 2; ++mi) {
          const int qq = q0 + mi * 16 + r;
          #pragma unroll
          for (int kj = 0; kj < 4; ++kj)
            #pragma unroll
            for (int jj = 0; jj < 4; ++jj) {
              const int kk = t * 64 + kj * 16 + 4 * g + jj;
              if (kk > qq) s[mi][kj][jj] = -3.0e38f;
            }
        }
      }

      #pragma unroll
      for (int mi = 0; mi < 2; ++mi) {
        const float a0 = fmaxf(fmaxf(s[mi][0][0], s[mi][0][1]), fmaxf(s[mi][0][2], s[mi][0][3]));
        const float a1 = fmaxf(fmaxf(s[mi][1][0], s[mi][1][1]), fmaxf(s[mi][1][2], s[mi][1][3]));
        const float a2 = fmaxf(fmaxf(s[mi][2][0], s[mi][2][1]), fmaxf(s[mi][2][2], s[mi][2][3]));
        const float a3 = fmaxf(fmaxf(s[mi][3][0], s[mi][3][1]), fmaxf(s[mi][3][2], s[mi][3][3]));
        const float lmxs = fmaxf(fmaxf(a0, a1), fmaxf(a2, a3)) * scale2;
        if (__any(lmxs > mrun[mi] + THR)) {    // rare: reduce + per-lane rescale
          float mx = lmxs;
          mx = fmaxf(mx, __shfl_xor(mx, 16));
          mx = fmaxf(mx, __shfl_xor(mx, 32));
          const float mnew = fmaxf(mrun[mi], mx);
          const float al = exp2v(mrun[mi] - mnew);
          mrun[mi] = mnew;
          lpart[mi] *= al;
          o[0][mi] *= al;                      // q lane-indexed: plain multiply
          o[1][mi] *= al;
        }
        #pragma unroll
        for (int kj = 0; kj < 4; ++kj)
          #pragma unroll
          for (int jj = 0; jj < 4; ++jj) {
            const float pv = exp2v(fmaf(s[mi][kj][jj], scale2, -mrun[mi]));
            s[mi][kj][jj] = pv;
            lpart[mi] += pv;
          }
      }

      // PV in-register: O^T[d][q] += V^T[d][k] * P^T[k][q]
      __builtin_amdgcn_s_setprio(1);
      #pragma unroll
      for (int kj = 0; kj < 4; ++kj) {
        const bf16x4 pf0 = pack4(s[0][kj]);
        const bf16x4 pf1 = pack4(s[1][kj]);
        #pragma unroll
        for (int di = 0; di < 2; ++di) {
          o[di][0] = mfma16bf(vf[di][kj], pf0, o[di][0]);
          o[di][1] = mfma16bf(vf[di][kj], pf1, o[di][1]);
        }
      }
      __builtin_amdgcn_s_setprio(0);
    }
    if (pf) writeV(cur ^ 1);                   // land V after compute (T14)
    __syncthreads();
    cur ^= 1;
  }

  // epilogue: per-wave l reduction (2 shfl) + direct store (no merge)
  #pragma unroll
  for (int mi = 0; mi < 2; ++mi) {
    float lr = lpart[mi];
    lr += __shfl_xor(lr, 16);
    lr += __shfl_xor(lr, 32);
    const float li = 1.0f / lr;
    const size_t row = tok0 + q0 + mi * 16 + r;
    #pragma unroll
    for (int di = 0; di < 2; ++di) {
      const u32 d0 = cvtpk_bf16(o[di][mi][0] * li, o[di][mi][1] * li);
      const u32 d1 = cvtpk_bf16(o[di][mi][2] * li, o[di][mi][3] * li);
      *(uint2*)&ctx[row * 384 + h * 32 + di * 16 + 4 * g] = make_uint2(d0, d1);
    }
  }
}

// ---------------------------------------------------------------------------
extern "C" void kernel_launch(void* const* d_in, const int* in_sizes, int n_in,
                              void* d_out, int out_size, void* d_ws, size_t ws_size,
                              hipStream_t stream) {
  const float* x      = (const float*)d_in[0];
  const float* W_attn = (const float*)d_in[1];
  const float* b_attn = (const float*)d_in[2];
  const float* P_q    = (const float*)d_in[3];
  const float* P_k    = (const float*)d_in[4];
  const float* P_v    = (const float*)d_in[5];
  const float* W_back = (const float*)d_in[6];
  const float* W_proj = (const float*)d_in[7];
  const float* b_proj = (const float*)d_in[8];

  char* ws = (char*)d_ws;
  u16*   x_bf   = (u16*)(ws);               // 8192x768 bf16
  u16*   ctx    = (u16*)(ws);               // 8192x384, aliases dead x_bf
  u16*   Wat_bf = (u16*)(ws + 12582912);    // 768x2304
  u16*   PT     = (u16*)(ws + 16121856);    // 1152x768
  u16*   Wbk_bf = (u16*)(ws + 17891328);    // 384x768
  u16*   WprT   = (u16*)(ws + 18481152);    // 768x768
  u16*   WcT    = (u16*)(ws + 19660800);    // 1152x768
  u16*   WbpT   = (u16*)(ws + 21430272);    // 768x384
  float* bc     = (float*)(ws + 22020096);  // 1152
  u16*   QKbuf  = (u16*)d_out;                          // 8192x768 (dead before gemm_out)
  u16*   VTbuf  = (u16*)((char*)d_out + 12582912);      // 384xVLD (dead before gemm_out)
  float* out    = (float*)d_out;

  prep_all<<<9600, 256, 0, stream>>>(x, W_attn, W_back, P_q, P_k, P_v, W_proj,
                                     x_bf, Wat_bf, Wbk_bf, PT, WprT);
  gemm_prep<<<80, 256, 0, stream>>>(PT, Wat_bf, WprT, Wbk_bf, b_attn, WcT, WbpT, bc);
  gemm_qkvt<<<288, 512, 0, stream>>>(x_bf, WcT, bc, QKbuf, VTbuf);
  attn_kernel<<<768, 256, 0, stream>>>(QKbuf, VTbuf, ctx);
  gemm_out<<<192, 512, 0, stream>>>(ctx, WbpT, b_proj, out);
}

// Round 12
// 120.568 us; speedup vs baseline: 1.0178x; 1.0178x over previous
//
#include <hip/hip_runtime.h>
#include <math.h>

// ---------------------------------------------------------------------------
// PatchedCausalSelfAttention  B=4 S=2048 D=768 DC=384 H=12 HD=32
//   prep_all : casts + transposes                        (1 launch)
//   gemm_prep: WcT[1152][768], WbpT[768][384], bc        (1 launch)
//   gemm_qkvt: QKbuf[8192][768], VT[384][8320-pad]       (1 launch)
//   attn     : ctx[8192][384] flash-causal. 4-wave blocks, 128 q-rows/block,
//              KVBLK=128 staged per barrier (2x64-k halves computed serially,
//              same reg footprint) -> heavy blocks 16 steps, was 32.
//   gemm_out : out[8192][768] fp32
// GEMMs: R9 config verbatim (best, 120.9us): 128x128 BK=32 depth-3 asm
// pipeline, counted vmcnt 8/4/0, XCD-chunked. R10's byte-model test failed
// (25% fewer staged bytes -> slower); ten variants bracket qkvt at 40.4us =
// the structural floor for this K=768-thin shape (m102 curve agrees).
// attn: R1-proven global heavy-first mapping (R2's bh-major XCD map aliased
// same-size blocks onto one CU -> 1.9x max-CU load; do not reintroduce).
// ---------------------------------------------------------------------------

typedef unsigned short u16;
typedef unsigned int   u32;

#define VLD 8320   // VT leading dimension (elements)

using short8 = __attribute__((ext_vector_type(8))) short;  // 8 bf16
using bf16x4 = __attribute__((ext_vector_type(4))) short;  // 4 bf16
using f32x4  = __attribute__((ext_vector_type(4))) float;

__device__ __forceinline__ u16 f2bf(float f) {
  u32 u = __builtin_bit_cast(u32, f);
  u = (u + 0x7fffu + ((u >> 16) & 1u)) >> 16;   // RNE
  return (u16)u;
}

__device__ __forceinline__ float b2f(u16 b) {
  return __builtin_bit_cast(float, (u32)b << 16);
}

__device__ __forceinline__ u32 cvtpk_bf16(float lo, float hi) {
  u32 d;
  asm("v_cvt_pk_bf16_f32 %0, %1, %2" : "=v"(d) : "v"(lo), "v"(hi));
  return d;
}

__device__ __forceinline__ bf16x4 pack4(const f32x4 v) {
  union { u32 u[2]; bf16x4 s; } c;
  c.u[0] = cvtpk_bf16(v[0], v[1]);
  c.u[1] = cvtpk_bf16(v[2], v[3]);
  return c.s;
}

// single-instruction 2^x (v_exp_f32). Large-negative inputs underflow to 0.
__device__ __forceinline__ float exp2v(float x) {
  return __builtin_amdgcn_exp2f(x);
}

__device__ __forceinline__ f32x4 mfma16bf(bf16x4 a, bf16x4 b, f32x4 c) {
#if __has_builtin(__builtin_amdgcn_mfma_f32_16x16x16bf16_1k)
  return __builtin_amdgcn_mfma_f32_16x16x16bf16_1k(a, b, c, 0, 0, 0);
#elif __has_builtin(__builtin_amdgcn_mfma_f32_16x16x16_bf16)
  return __builtin_amdgcn_mfma_f32_16x16x16_bf16(a, b, c, 0, 0, 0);
#else
  f32x4 d;  // non-volatile: scheduler may interleave with surrounding VALU
  asm("v_mfma_f32_16x16x16_bf16 %0, %1, %2, %3"
      : "=v"(d) : "v"(a), "v"(b), "v"(c));
  return d;
#endif
}

__device__ __forceinline__ void gload_lds16(const void* g, void* l) {
  __builtin_amdgcn_global_load_lds((__attribute__((address_space(1))) u32*)g,
                                   (__attribute__((address_space(3))) u32*)l,
                                   16, 0, 0);
}

// LDS byte offset of a pointer known to be in LDS (generic -> AS3 -> int).
__device__ __forceinline__ u32 lds_u32(const void* p) {
  return (u32)(size_t)(const __attribute__((address_space(3))) char*)p;
}

// ---------------- mega-prep: casts + transposes -----------------------------
__global__ __launch_bounds__(256) void prep_all(
    const float* __restrict__ x, const float* __restrict__ Wa,
    const float* __restrict__ Wb, const float* __restrict__ Pq,
    const float* __restrict__ Pk, const float* __restrict__ Pv,
    const float* __restrict__ Wp,
    u16* __restrict__ x_bf, u16* __restrict__ Wat_bf, u16* __restrict__ Wbk_bf,
    u16* __restrict__ PT, u16* __restrict__ WprT) {
  __shared__ float t[32][33];
  const int blk = blockIdx.x, tid = threadIdx.x;
  if (blk < 8160) {  // vectorized casts (x4 floats per thread)
    const float* src; u16* dst; int i;
    if (blk < 6144)      { src = x;  dst = x_bf;   i = blk * 256 + tid; }
    else if (blk < 7872) { src = Wa; dst = Wat_bf; i = (blk - 6144) * 256 + tid; }
    else                 { src = Wb; dst = Wbk_bf; i = (blk - 7872) * 256 + tid; }
    const float4 v = ((const float4*)src)[i];
    ((ushort4*)dst)[i] = make_ushort4(f2bf(v.x), f2bf(v.y), f2bf(v.z), f2bf(v.w));
    return;
  }
  // transpose+cast 32x32 tiles
  const float* src; u16* dst; int C, R, bx, by;
  if (blk < 8448)      { src = Pq; dst = PT;             R = 768; C = 384; int t2 = blk - 8160; bx = t2 % 12; by = t2 / 12; }
  else if (blk < 8736) { src = Pk; dst = PT + 384 * 768; R = 768; C = 384; int t2 = blk - 8448; bx = t2 % 12; by = t2 / 12; }
  else if (blk < 9024) { src = Pv; dst = PT + 768 * 768; R = 768; C = 384; int t2 = blk - 8736; bx = t2 % 12; by = t2 / 12; }
  else                 { src = Wp; dst = WprT;           R = 768; C = 768; int t2 = blk - 9024; bx = t2 % 24; by = t2 / 24; }
  const int c0 = bx * 32, r0 = by * 32, tx = tid & 31, ty = tid >> 5;
  for (int i = ty; i < 32; i += 8)
    t[i][tx] = src[(size_t)(r0 + i) * C + c0 + tx];
  __syncthreads();
  for (int i = ty; i < 32; i += 8)
    dst[(size_t)(c0 + i) * R + r0 + tx] = f2bf(t[tx][i]);
}

// ---------------- bf16 MFMA GEMM tile 128x128, depth-3 asm pipeline ---------
// BK=32 TRIPLE-buffered (3 x 8KB A + 3 x 8KB B = 48KB). 12 loads in flight
// per thread. Steady state: vmcnt(8) retires only tile t; stage t+3 after
// the read-barrier. No vmcnt(0) until the final two steps.
template<int OBF16>
__device__ __forceinline__ void gemm_tile(
    const u16* __restrict__ A, const u16* __restrict__ BT,
    const float* __restrict__ bias, void* __restrict__ Cv,
    int K, int lda, int ldb, int ldc, int m0, int n0, int biasmode, bool slab,
    u16* As, u16* Bs) {
  const int tid = threadIdx.x;
  const int l = tid & 63, w = tid >> 6;
  const int r = l & 15, g = l >> 4;
  const int koff = slab ? (m0 / 384) * 768 : 0;
  const u16* Ap = A + ((size_t)m0 + w * 16 + r) * lda + g * 8;
  const u16* Bp = BT + ((size_t)n0 + w * 16 + r) * ldb + koff + g * 8;
  f32x4 acc[4][4] = {};
  const int wma = (w >> 1) * 4, wnb = (w & 1) * 4;
  const int nk = K >> 5;   // >= 12 for all call sites

  const u32 abase = lds_u32(As) + (u32)(wma * 1024 + l * 16);
  const u32 bbase = lds_u32(Bs) + (u32)(wnb * 1024 + l * 16);

  auto stage = [&](int kt, int buf) {
    const int o = buf * 4096;
    gload_lds16(Ap + kt,                    &As[o + (size_t)tid * 8]);
    gload_lds16(Ap + kt + (size_t)64 * lda, &As[o + 2048 + (size_t)tid * 8]);
    gload_lds16(Bp + kt,                    &Bs[o + (size_t)tid * 8]);
    gload_lds16(Bp + kt + (size_t)64 * ldb, &Bs[o + 2048 + (size_t)tid * 8]);
  };

  stage(0, 0);
  stage(32, 1);
  stage(64, 2);                     // 12 loads in flight
  int cur = 0;
  for (int t = 0; t < nk; ++t) {
    if (t + 2 < nk)      asm volatile("s_waitcnt vmcnt(8)" ::: "memory");
    else if (t + 1 < nk) asm volatile("s_waitcnt vmcnt(4)" ::: "memory");
    else                 asm volatile("s_waitcnt vmcnt(0)" ::: "memory");
    __builtin_amdgcn_s_barrier();   // tile t resident in buf cur (all waves)
    __builtin_amdgcn_sched_barrier(0);
    const u32 off = (u32)(cur * 8192);  // buffer stride 8KB
    short8 af[4], bfr[4];
    #pragma unroll
    for (int i = 0; i < 4; ++i) {
      asm volatile("ds_read_b128 %0, %1" : "=v"(af[i])  : "v"(abase + off + 1024u * i));
      asm volatile("ds_read_b128 %0, %1" : "=v"(bfr[i]) : "v"(bbase + off + 1024u * i));
    }
    asm volatile("s_waitcnt lgkmcnt(0)" ::: "memory");
    __builtin_amdgcn_sched_barrier(0);  // rule 18: nothing hoists above the wait
    __builtin_amdgcn_s_barrier();       // all waves' reads done -> buf cur free
    __builtin_amdgcn_sched_barrier(0);
    if (t + 3 < nk) stage((t + 3) << 5, cur);  // refill freed buffer, in flight
    #pragma unroll
    for (int mi = 0; mi < 4; ++mi)
      #pragma unroll
      for (int ni = 0; ni < 4; ++ni)
        acc[mi][ni] = __builtin_amdgcn_mfma_f32_16x16x32_bf16(af[mi], bfr[ni],
                                                              acc[mi][ni], 0, 0, 0);
    cur = (cur == 2) ? 0 : cur + 1;
  }

  const int row0 = m0 + (w >> 1) * 64, col0 = n0 + (w & 1) * 64;
  #pragma unroll
  for (int ni = 0; ni < 4; ++ni) {
    const int col = col0 + ni * 16 + r;
    const float bvc = (biasmode == 1) ? bias[col] : 0.f;
    #pragma unroll
    for (int mi = 0; mi < 4; ++mi)
      #pragma unroll
      for (int j = 0; j < 4; ++j) {
        const int row = row0 + mi * 16 + 4 * g + j;
        float bv = bvc;
        if (biasmode == 2) bv = bias[row];
        const float v = acc[mi][ni][j] + bv;
        if (OBF16) ((u16*)Cv)[(size_t)row * ldc + col] = f2bf(v);
        else       ((float*)Cv)[(size_t)row * ldc + col] = v;
      }
  }
}

// prep GEMMs: [0,54) WcT; [54,72) WbpT; [72,80) bc = ba(slab) . PT rows
__global__ __launch_bounds__(256, 3) void gemm_prep(
    const u16* __restrict__ PT, const u16* __restrict__ Wat,
    const u16* __restrict__ WprT, const u16* __restrict__ Wbk,
    const float* __restrict__ ba,
    u16* __restrict__ WcT, u16* __restrict__ WbpT, float* __restrict__ bc) {
  __shared__ alignas(16) u16 As[12288], Bs[12288];
  const int t = blockIdx.x;
  if (t < 54) {
    gemm_tile<1>(PT, Wat, nullptr, WcT, 768, 768, 2304, 768,
                 (t % 9) * 128, (t / 9) * 128, 0, true, As, Bs);
  } else if (t < 72) {
    const int t2 = t - 54;
    gemm_tile<1>(WprT, Wbk, nullptr, WbpT, 768, 768, 768, 384,
                 (t2 % 6) * 128, (t2 / 6) * 128, 0, false, As, Bs);
  } else {
    const int c = (t - 72) * 144 + threadIdx.x;
    if (threadIdx.x < 144 && c < 1152) {
      const int slab = c / 384;
      const float* bs = ba + slab * 768;
      const u16* row = PT + (size_t)c * 768;
      float s = 0.f;
      for (int jj = 0; jj < 96; ++jj) {
        const short8 v = *(const short8*)&row[jj * 8];
        #pragma unroll
        for (int e = 0; e < 8; ++e)
          s = fmaf(bs[jj * 8 + e], b2f((u16)v[e]), s);
      }
      bc[c] = s;
    }
  }
}

// main GEMMs, XCD-chunked: logical w groups the 9 jobs reading one 128-token
// x_bf strip (6 QK col-panels + 3 VT row-panels); xcd = t%8 round-robin.
__global__ __launch_bounds__(256, 3) void gemm_qkvt(
    const u16* __restrict__ x_bf, const u16* __restrict__ WcT,
    const float* __restrict__ bc, u16* __restrict__ QKbuf, u16* __restrict__ VTbuf) {
  __shared__ alignas(16) u16 As[12288], Bs[12288];
  const int t = blockIdx.x;                 // 576 = 8 xcd * 72
  const int w = (t & 7) * 72 + (t >> 3);    // XCD-chunked logical id
  const int s = w / 9, j = w % 9;           // token strip, sub-job
  if (j < 6) {
    gemm_tile<1>(x_bf, WcT, bc, QKbuf, 768, 768, 768, 768,
                 s * 128, j * 128, 1, false, As, Bs);
  } else {
    gemm_tile<1>(WcT + (size_t)768 * 768, x_bf, bc + 768, VTbuf, 768, 768, 768, VLD,
                 (j - 6) * 128, s * 128, 2, false, As, Bs);
  }
}

__global__ __launch_bounds__(256, 3) void gemm_out(
    const u16* __restrict__ ctx, const u16* __restrict__ WbpT,
    const float* __restrict__ bp, float* __restrict__ out) {
  __shared__ alignas(16) u16 As[12288], Bs[12288];
  const int t = blockIdx.x;                 // 384 = 8 xcd * 48
  const int w = (t & 7) * 48 + (t >> 3);    // XCD-chunked logical id
  gemm_tile<0>(ctx, WbpT, bp, out, 384, 384, 384, 768,
               (w / 6) * 128, (w % 6) * 128, 1, false, As, Bs);
}

// ---------------- causal flash attention, KVBLK=128, 4-wave blocks ----------
// grid: 768 blocks x 256 thr (heavy chunks first, global order — R1-proven).
// Block = 128 q-rows of one (b,h); wave w owns rows [cc*128 + w*32, +32).
// Per barrier-step: stage a 128-k K tile (global_load_lds, 2 chunks/thread)
// and a 32x128 V tile (reg->LDS, 2 uint4/thread, issue-early/write-late T14);
// compute as TWO serial 64-k halves (same reg footprint as KVBLK=64, so
// VGPR~52 and 4 blocks/CU hold). Heavy blocks: 16 steps, was 32. Half h of
// tile t skipped when 128t+64h > q0+31; per-element mask only at t==last.
__global__ __launch_bounds__(256, 4) void attn_kernel(
    const u16* __restrict__ QK, const u16* __restrict__ VT,
    u16* __restrict__ ctx) {
  __shared__ alignas(16) u16 Ks[2][4096];       // 8KB per buffer (128k x 32hd)
  __shared__ alignas(16) u16 Vs[2][32 * 136];   // 8.5KB per buffer (padded rows)
  const int tid = threadIdx.x;
  const int w = tid >> 6, l = tid & 63;
  const int r = l & 15, g = l >> 4;
  const int idx = blockIdx.x;
  const int cc = 15 - idx / 48;                // q-chunk (128 rows), heavy first
  const int bh = idx % 48;
  const int b = bh / 12, h = bh % 12;
  const size_t tok0 = (size_t)b * 2048;
  const int q0 = cc * 128 + w * 32;            // this wave's q-strip base
  const u16* Qb = QK + (tok0 + q0) * 768 + h * 32;
  const u16* Kb = QK + tok0 * 768 + 384 + h * 32;
  const u16* Vb = VT + (size_t)(h * 32) * VLD + b * 2048;
  const float scale2 = 0.25500526474f;         // (1/sqrt(32))*log2(e)
  const float THR = 8.0f;                      // defer-max threshold (T13)
  const f32x4 fz = {0.f, 0.f, 0.f, 0.f};

  short8 qf[2];
  qf[0] = *(const short8*)&Qb[(size_t)r * 768 + 8 * g];
  qf[1] = *(const short8*)&Qb[(size_t)(16 + r) * 768 + 8 * g];

  float mrun[2] = {-3.0e38f, -3.0e38f};
  float lpart[2] = {0.f, 0.f};                 // per-lane partial row sums
  f32x4 o[2][2] = {};                          // o[di][mi]: d=16di+4g+jj, q=16mi+r
  const int nt = cc + 1;                       // 128-k tiles in this chunk

  // staging roles (fixed per thread; all 256 threads do K and V)
  const int krow = ((tid >> 6) << 4) + (tid & 15);   // K chunk row (0..63)
  const int kcol = ((tid >> 4) & 3) * 8;             // K chunk col
  const int vd   = tid >> 3;                          // V row d (0..31)
  const int vkc  = (tid & 7) * 8;                     // V col chunk (0..56)

  uint4 vreg0, vreg1;
  auto stageK = [&](int t, int buf) {
    gload_lds16(&Kb[(size_t)(t * 128 + krow) * 768 + kcol],      &Ks[buf][(size_t)tid * 8]);
    gload_lds16(&Kb[(size_t)(t * 128 + 64 + krow) * 768 + kcol], &Ks[buf][(size_t)(tid + 256) * 8]);
  };
  auto loadV = [&](int t) {
    vreg0 = *(const uint4*)&Vb[(size_t)vd * VLD + t * 128 + vkc];
    vreg1 = *(const uint4*)&Vb[(size_t)vd * VLD + t * 128 + 64 + vkc];
  };
  auto writeV = [&](int buf) {
    *(uint4*)&Vs[buf][vd * 136 + vkc]      = vreg0;
    *(uint4*)&Vs[buf][vd * 136 + 64 + vkc] = vreg1;
  };

  loadV(0); stageK(0, 0); writeV(0);
  __syncthreads();
  int cur = 0;
  for (int t = 0; t < nt; ++t) {
    const bool pf = (t + 1 < nt);
    if (pf) { loadV(t + 1); stageK(t + 1, cur ^ 1); }  // issue next tile early
    #pragma unroll
    for (int hh = 0; hh < 2; ++hh) {
      const int k0 = t * 128 + hh * 64;
      if (k0 > q0 + 31) continue;              // wave fully above this half
      // K fragments: lane holds K[k=k0+16kj+r][hd=8g..]
      short8 kf[4];
      #pragma unroll
      for (int kj = 0; kj < 4; ++kj)
        kf[kj] = *(const short8*)&Ks[cur][(hh * 256 + kj * 64 + l) * 8];
      // V^T fragments: lane holds VT[d=16di+r][k=k0+16kj+4g..+3]
      bf16x4 vf[2][4];
      #pragma unroll
      for (int di = 0; di < 2; ++di)
        #pragma unroll
        for (int kj = 0; kj < 4; ++kj)
          vf[di][kj] = *(const bf16x4*)&Vs[cur][(16 * di + r) * 136 + hh * 64 + kj * 16 + 4 * g];

      // S^T = K Q^T : lane holds S[k=k0+16kj+4g+jj][q=16mi+r]  (raw)
      f32x4 s[2][4];
      __builtin_amdgcn_s_setprio(1);
      #pragma unroll
      for (int kj = 0; kj < 4; ++kj)
        #pragma unroll
        for (int mi = 0; mi < 2; ++mi)
          s[mi][kj] = __builtin_amdgcn_mfma_f32_16x16x32_bf16(kf[kj], qf[mi], fz, 0, 0, 0);
      __builtin_amdgcn_s_setprio(0);

      if (t == nt - 1) {  // only the diagonal tile needs masking
        #pragma unroll
        for (int mi = 0; mi < 2; ++mi) {
          const int qq = q0 + mi * 16 + r;
          #pragma unroll
          for (int kj = 0; kj < 4; ++kj)
            #pragma unroll
            for (int jj = 0; jj < 4; ++jj) {
              const int kk = k0 + kj * 16 + 4 * g + jj;
              if (kk > qq) s[mi][kj][jj] = -3.0e38f;
            }
        }
      }

      #pragma unroll
      for (int mi = 0; mi < 2; ++mi) {
        const float a0 = fmaxf(fmaxf(s[mi][0][0], s[mi][0][1]), fmaxf(s[mi][0][2], s[mi][0][3]));
        const float a1 = fmaxf(fmaxf(s[mi][1][0], s[mi][1][1]), fmaxf(s[mi][1][2], s[mi][1][3]));
        const float a2 = fmaxf(fmaxf(s[mi][2][0], s[mi][2][1]), fmaxf(s[mi][2][2], s[mi][2][3]));
        const float a3 = fmaxf(fmaxf(s[mi][3][0], s[mi][3][1]), fmaxf(s[mi][3][2], s[mi][3][3]));
        const float lmxs = fmaxf(fmaxf(a0, a1), fmaxf(a2, a3)) * scale2;
        if (__any(lmxs > mrun[mi] + THR)) {    // rare: reduce + per-lane rescale
          float mx = lmxs;
          mx = fmaxf(mx, __shfl_xor(mx, 16));
          mx = fmaxf(mx, __shfl_xor(mx, 32));
          const float mnew = fmaxf(mrun[mi], mx);
          const float al = exp2v(mrun[mi] - mnew);
          mrun[mi] = mnew;
          lpart[mi] *= al;
          o[0][mi] *= al;                      // q lane-indexed: plain multiply
          o[1][mi] *= al;
        }
        #pragma unroll
        for (int kj = 0; kj < 4; ++kj)
          #pragma unroll
          for (int jj = 0; jj < 4; ++jj) {
            const float pv = exp2v(fmaf(s[mi][kj][jj], scale2, -mrun[mi]));
            s[mi][kj][jj] = pv;
            lpart[mi] += pv;
          }
      }

      // PV in-register: O^T[d][q] += V^T[d][k] * P^T[k][q]
      __builtin_amdgcn_s_setprio(1);
      #pragma unroll
      for (int kj = 0; kj < 4; ++kj) {
        const bf16x4 pf0 = pack4(s[0][kj]);
        const bf16x4 pf1 = pack4(s[1][kj]);
        #pragma unroll
        for (int di = 0; di < 2; ++di) {
          o[di][0] = mfma16bf(vf[di][kj], pf0, o[di][0]);
          o[di][1] = mfma16bf(vf[di][kj], pf1, o[di][1]);
        }
      }
      __builtin_amdgcn_s_setprio(0);
    }
    if (pf) writeV(cur ^ 1);                   // land V after compute (T14)
    __syncthreads();
    cur ^= 1;
  }

  // epilogue: per-wave l reduction (2 shfl) + direct store (no merge)
  #pragma unroll
  for (int mi = 0; mi < 2; ++mi) {
    float lr = lpart[mi];
    lr += __shfl_xor(lr, 16);
    lr += __shfl_xor(lr, 32);
    const float li = 1.0f / lr;
    const size_t row = tok0 + q0 + mi * 16 + r;
    #pragma unroll
    for (int di = 0; di < 2; ++di) {
      const u32 d0 = cvtpk_bf16(o[di][mi][0] * li, o[di][mi][1] * li);
      const u32 d1 = cvtpk_bf16(o[di][mi][2] * li, o[di][mi][3] * li);
      *(uint2*)&ctx[row * 384 + h * 32 + di * 16 + 4 * g] = make_uint2(d0, d1);
    }
  }
}

// ---------------------------------------------------------------------------
extern "C" void kernel_launch(void* const* d_in, const int* in_sizes, int n_in,
                              void* d_out, int out_size, void* d_ws, size_t ws_size,
                              hipStream_t stream) {
  const float* x      = (const float*)d_in[0];
  const float* W_attn = (const float*)d_in[1];
  const float* b_attn = (const float*)d_in[2];
  const float* P_q    = (const float*)d_in[3];
  const float* P_k    = (const float*)d_in[4];
  const float* P_v    = (const float*)d_in[5];
  const float* W_back = (const float*)d_in[6];
  const float* W_proj = (const float*)d_in[7];
  const float* b_proj = (const float*)d_in[8];

  char* ws = (char*)d_ws;
  u16*   x_bf   = (u16*)(ws);               // 8192x768 bf16
  u16*   ctx    = (u16*)(ws);               // 8192x384, aliases dead x_bf
  u16*   Wat_bf = (u16*)(ws + 12582912);    // 768x2304
  u16*   PT     = (u16*)(ws + 16121856);    // 1152x768
  u16*   Wbk_bf = (u16*)(ws + 17891328);    // 384x768
  u16*   WprT   = (u16*)(ws + 18481152);    // 768x768
  u16*   WcT    = (u16*)(ws + 19660800);    // 1152x768
  u16*   WbpT   = (u16*)(ws + 21430272);    // 768x384
  float* bc     = (float*)(ws + 22020096);  // 1152
  u16*   QKbuf  = (u16*)d_out;                          // 8192x768 (dead before gemm_out)
  u16*   VTbuf  = (u16*)((char*)d_out + 12582912);      // 384xVLD (dead before gemm_out)
  float* out    = (float*)d_out;

  prep_all<<<9600, 256, 0, stream>>>(x, W_attn, W_back, P_q, P_k, P_v, W_proj,
                                     x_bf, Wat_bf, Wbk_bf, PT, WprT);
  gemm_prep<<<80, 256, 0, stream>>>(PT, Wat_bf, WprT, Wbk_bf, b_attn, WcT, WbpT, bc);
  gemm_qkvt<<<576, 256, 0, stream>>>(x_bf, WcT, bc, QKbuf, VTbuf);
  attn_kernel<<<768, 256, 0, stream>>>(QKbuf, VTbuf, ctx);
  gemm_out<<<384, 256, 0, stream>>>(ctx, WbpT, b_proj, out);
}

// Round 13
// 118.455 us; speedup vs baseline: 1.0360x; 1.0178x over previous
//
#include <hip/hip_runtime.h>
#include <math.h>

// ---------------------------------------------------------------------------
// PatchedCausalSelfAttention  B=4 S=2048 D=768 DC=384 H=12 HD=32
//   prep_w   : weight casts + transposes (3456 blocks)   (1 launch)
//   gemm_prep: FUSED: blocks 0-79 WcT/WbpT/bc GEMM jobs, blocks 80-6223
//              x fp32->bf16 cast. The 80 GEMM blocks leave >65% of CUs idle
//              for their ~18us block latency; the 6144 independent cast
//              blocks fill them (x-cast needs only x; GEMM jobs need only
//              prep_w outputs) -> x-cast leaves the critical path.
//   gemm_qkvt: QKbuf[8192][768], VT[384][8320-pad]       (1 launch)
//   attn     : ctx[8192][384] flash-causal, KVBLK=128.
//   gemm_out : out[8192][768] fp32
// GEMMs: R9 config (structural floor): 128x128 BK=32 depth-3 asm pipeline,
// counted vmcnt 8/4/0, XCD-chunked. Eleven variants (sync structure, depth,
// occupancy, tile shape, staged bytes, no-LDS) bracket qkvt at 40.4us
// (~359 TF, matches m102 curve for K=768-thin shapes) — do not re-tune.
// attn: R1-proven global heavy-first mapping; KVBLK=128 (R11, neutral-best).
// ---------------------------------------------------------------------------

typedef unsigned short u16;
typedef unsigned int   u32;

#define VLD 8320   // VT leading dimension (elements)

using short8 = __attribute__((ext_vector_type(8))) short;  // 8 bf16
using bf16x4 = __attribute__((ext_vector_type(4))) short;  // 4 bf16
using f32x4  = __attribute__((ext_vector_type(4))) float;

__device__ __forceinline__ u16 f2bf(float f) {
  u32 u = __builtin_bit_cast(u32, f);
  u = (u + 0x7fffu + ((u >> 16) & 1u)) >> 16;   // RNE
  return (u16)u;
}

__device__ __forceinline__ float b2f(u16 b) {
  return __builtin_bit_cast(float, (u32)b << 16);
}

__device__ __forceinline__ u32 cvtpk_bf16(float lo, float hi) {
  u32 d;
  asm("v_cvt_pk_bf16_f32 %0, %1, %2" : "=v"(d) : "v"(lo), "v"(hi));
  return d;
}

__device__ __forceinline__ bf16x4 pack4(const f32x4 v) {
  union { u32 u[2]; bf16x4 s; } c;
  c.u[0] = cvtpk_bf16(v[0], v[1]);
  c.u[1] = cvtpk_bf16(v[2], v[3]);
  return c.s;
}

// single-instruction 2^x (v_exp_f32). Large-negative inputs underflow to 0.
__device__ __forceinline__ float exp2v(float x) {
  return __builtin_amdgcn_exp2f(x);
}

__device__ __forceinline__ f32x4 mfma16bf(bf16x4 a, bf16x4 b, f32x4 c) {
#if __has_builtin(__builtin_amdgcn_mfma_f32_16x16x16bf16_1k)
  return __builtin_amdgcn_mfma_f32_16x16x16bf16_1k(a, b, c, 0, 0, 0);
#elif __has_builtin(__builtin_amdgcn_mfma_f32_16x16x16_bf16)
  return __builtin_amdgcn_mfma_f32_16x16x16_bf16(a, b, c, 0, 0, 0);
#else
  f32x4 d;  // non-volatile: scheduler may interleave with surrounding VALU
  asm("v_mfma_f32_16x16x16_bf16 %0, %1, %2, %3"
      : "=v"(d) : "v"(a), "v"(b), "v"(c));
  return d;
#endif
}

__device__ __forceinline__ void gload_lds16(const void* g, void* l) {
  __builtin_amdgcn_global_load_lds((__attribute__((address_space(1))) u32*)g,
                                   (__attribute__((address_space(3))) u32*)l,
                                   16, 0, 0);
}

// LDS byte offset of a pointer known to be in LDS (generic -> AS3 -> int).
__device__ __forceinline__ u32 lds_u32(const void* p) {
  return (u32)(size_t)(const __attribute__((address_space(3))) char*)p;
}

// ---------------- weight prep: casts + transposes ---------------------------
__global__ __launch_bounds__(256) void prep_w(
    const float* __restrict__ Wa, const float* __restrict__ Wb,
    const float* __restrict__ Pq, const float* __restrict__ Pk,
    const float* __restrict__ Pv, const float* __restrict__ Wp,
    u16* __restrict__ Wat_bf, u16* __restrict__ Wbk_bf,
    u16* __restrict__ PT, u16* __restrict__ WprT) {
  __shared__ float t[32][33];
  const int blk = blockIdx.x, tid = threadIdx.x;
  if (blk < 2016) {  // vectorized weight casts (x4 floats per thread)
    const float* src; u16* dst; int i;
    if (blk < 1728) { src = Wa; dst = Wat_bf; i = blk * 256 + tid; }
    else            { src = Wb; dst = Wbk_bf; i = (blk - 1728) * 256 + tid; }
    const float4 v = ((const float4*)src)[i];
    ((ushort4*)dst)[i] = make_ushort4(f2bf(v.x), f2bf(v.y), f2bf(v.z), f2bf(v.w));
    return;
  }
  // transpose+cast 32x32 tiles
  const int b2 = blk - 2016;   // 0..1439
  const float* src; u16* dst; int C, R, bx, by;
  if (b2 < 288)      { src = Pq; dst = PT;             R = 768; C = 384; bx = b2 % 12; by = b2 / 12; }
  else if (b2 < 576) { src = Pk; dst = PT + 384 * 768; R = 768; C = 384; int t2 = b2 - 288; bx = t2 % 12; by = t2 / 12; }
  else if (b2 < 864) { src = Pv; dst = PT + 768 * 768; R = 768; C = 384; int t2 = b2 - 576; bx = t2 % 12; by = t2 / 12; }
  else               { src = Wp; dst = WprT;           R = 768; C = 768; int t2 = b2 - 864; bx = t2 % 24; by = t2 / 24; }
  const int c0 = bx * 32, r0 = by * 32, tx = tid & 31, ty = tid >> 5;
  for (int i = ty; i < 32; i += 8)
    t[i][tx] = src[(size_t)(r0 + i) * C + c0 + tx];
  __syncthreads();
  for (int i = ty; i < 32; i += 8)
    dst[(size_t)(c0 + i) * R + r0 + tx] = f2bf(t[tx][i]);
}

// ---------------- bf16 MFMA GEMM tile 128x128, depth-3 asm pipeline ---------
// BK=32 TRIPLE-buffered (3 x 8KB A + 3 x 8KB B = 48KB). 12 loads in flight
// per thread. Steady state: vmcnt(8) retires only tile t; stage t+3 after
// the read-barrier. No vmcnt(0) until the final two steps.
template<int OBF16>
__device__ __forceinline__ void gemm_tile(
    const u16* __restrict__ A, const u16* __restrict__ BT,
    const float* __restrict__ bias, void* __restrict__ Cv,
    int K, int lda, int ldb, int ldc, int m0, int n0, int biasmode, bool slab,
    u16* As, u16* Bs) {
  const int tid = threadIdx.x;
  const int l = tid & 63, w = tid >> 6;
  const int r = l & 15, g = l >> 4;
  const int koff = slab ? (m0 / 384) * 768 : 0;
  const u16* Ap = A + ((size_t)m0 + w * 16 + r) * lda + g * 8;
  const u16* Bp = BT + ((size_t)n0 + w * 16 + r) * ldb + koff + g * 8;
  f32x4 acc[4][4] = {};
  const int wma = (w >> 1) * 4, wnb = (w & 1) * 4;
  const int nk = K >> 5;   // >= 12 for all call sites

  const u32 abase = lds_u32(As) + (u32)(wma * 1024 + l * 16);
  const u32 bbase = lds_u32(Bs) + (u32)(wnb * 1024 + l * 16);

  auto stage = [&](int kt, int buf) {
    const int o = buf * 4096;
    gload_lds16(Ap + kt,                    &As[o + (size_t)tid * 8]);
    gload_lds16(Ap + kt + (size_t)64 * lda, &As[o + 2048 + (size_t)tid * 8]);
    gload_lds16(Bp + kt,                    &Bs[o + (size_t)tid * 8]);
    gload_lds16(Bp + kt + (size_t)64 * ldb, &Bs[o + 2048 + (size_t)tid * 8]);
  };

  stage(0, 0);
  stage(32, 1);
  stage(64, 2);                     // 12 loads in flight
  int cur = 0;
  for (int t = 0; t < nk; ++t) {
    if (t + 2 < nk)      asm volatile("s_waitcnt vmcnt(8)" ::: "memory");
    else if (t + 1 < nk) asm volatile("s_waitcnt vmcnt(4)" ::: "memory");
    else                 asm volatile("s_waitcnt vmcnt(0)" ::: "memory");
    __builtin_amdgcn_s_barrier();   // tile t resident in buf cur (all waves)
    __builtin_amdgcn_sched_barrier(0);
    const u32 off = (u32)(cur * 8192);  // buffer stride 8KB
    short8 af[4], bfr[4];
    #pragma unroll
    for (int i = 0; i < 4; ++i) {
      asm volatile("ds_read_b128 %0, %1" : "=v"(af[i])  : "v"(abase + off + 1024u * i));
      asm volatile("ds_read_b128 %0, %1" : "=v"(bfr[i]) : "v"(bbase + off + 1024u * i));
    }
    asm volatile("s_waitcnt lgkmcnt(0)" ::: "memory");
    __builtin_amdgcn_sched_barrier(0);  // rule 18: nothing hoists above the wait
    __builtin_amdgcn_s_barrier();       // all waves' reads done -> buf cur free
    __builtin_amdgcn_sched_barrier(0);
    if (t + 3 < nk) stage((t + 3) << 5, cur);  // refill freed buffer, in flight
    #pragma unroll
    for (int mi = 0; mi < 4; ++mi)
      #pragma unroll
      for (int ni = 0; ni < 4; ++ni)
        acc[mi][ni] = __builtin_amdgcn_mfma_f32_16x16x32_bf16(af[mi], bfr[ni],
                                                              acc[mi][ni], 0, 0, 0);
    cur = (cur == 2) ? 0 : cur + 1;
  }

  const int row0 = m0 + (w >> 1) * 64, col0 = n0 + (w & 1) * 64;
  #pragma unroll
  for (int ni = 0; ni < 4; ++ni) {
    const int col = col0 + ni * 16 + r;
    const float bvc = (biasmode == 1) ? bias[col] : 0.f;
    #pragma unroll
    for (int mi = 0; mi < 4; ++mi)
      #pragma unroll
      for (int j = 0; j < 4; ++j) {
        const int row = row0 + mi * 16 + 4 * g + j;
        float bv = bvc;
        if (biasmode == 2) bv = bias[row];
        const float v = acc[mi][ni][j] + bv;
        if (OBF16) ((u16*)Cv)[(size_t)row * ldc + col] = f2bf(v);
        else       ((float*)Cv)[(size_t)row * ldc + col] = v;
      }
  }
}

// FUSED prep2: blocks [0,54) WcT; [54,72) WbpT; [72,80) bc; [80,6224) x-cast.
// GEMM jobs at low blockIdx dispatch first; cast blocks fill the idle CUs.
__global__ __launch_bounds__(256, 3) void gemm_prep(
    const u16* __restrict__ PT, const u16* __restrict__ Wat,
    const u16* __restrict__ WprT, const u16* __restrict__ Wbk,
    const float* __restrict__ ba, const float* __restrict__ x,
    u16* __restrict__ WcT, u16* __restrict__ WbpT, float* __restrict__ bc,
    u16* __restrict__ x_bf) {
  __shared__ alignas(16) u16 As[12288], Bs[12288];
  const int t = blockIdx.x;
  if (t >= 80) {  // x fp32->bf16 cast (independent of the GEMM jobs)
    const int i = (t - 80) * 256 + threadIdx.x;
    const float4 v = ((const float4*)x)[i];
    ((ushort4*)x_bf)[i] = make_ushort4(f2bf(v.x), f2bf(v.y), f2bf(v.z), f2bf(v.w));
    return;
  }
  if (t < 54) {
    gemm_tile<1>(PT, Wat, nullptr, WcT, 768, 768, 2304, 768,
                 (t % 9) * 128, (t / 9) * 128, 0, true, As, Bs);
  } else if (t < 72) {
    const int t2 = t - 54;
    gemm_tile<1>(WprT, Wbk, nullptr, WbpT, 768, 768, 768, 384,
                 (t2 % 6) * 128, (t2 / 6) * 128, 0, false, As, Bs);
  } else {
    const int c = (t - 72) * 144 + threadIdx.x;
    if (threadIdx.x < 144 && c < 1152) {
      const int slab = c / 384;
      const float* bs = ba + slab * 768;
      const u16* row = PT + (size_t)c * 768;
      float s = 0.f;
      for (int jj = 0; jj < 96; ++jj) {
        const short8 v = *(const short8*)&row[jj * 8];
        #pragma unroll
        for (int e = 0; e < 8; ++e)
          s = fmaf(bs[jj * 8 + e], b2f((u16)v[e]), s);
      }
      bc[c] = s;
    }
  }
}

// main GEMMs, XCD-chunked: logical w groups the 9 jobs reading one 128-token
// x_bf strip (6 QK col-panels + 3 VT row-panels); xcd = t%8 round-robin.
__global__ __launch_bounds__(256, 3) void gemm_qkvt(
    const u16* __restrict__ x_bf, const u16* __restrict__ WcT,
    const float* __restrict__ bc, u16* __restrict__ QKbuf, u16* __restrict__ VTbuf) {
  __shared__ alignas(16) u16 As[12288], Bs[12288];
  const int t = blockIdx.x;                 // 576 = 8 xcd * 72
  const int w = (t & 7) * 72 + (t >> 3);    // XCD-chunked logical id
  const int s = w / 9, j = w % 9;           // token strip, sub-job
  if (j < 6) {
    gemm_tile<1>(x_bf, WcT, bc, QKbuf, 768, 768, 768, 768,
                 s * 128, j * 128, 1, false, As, Bs);
  } else {
    gemm_tile<1>(WcT + (size_t)768 * 768, x_bf, bc + 768, VTbuf, 768, 768, 768, VLD,
                 (j - 6) * 128, s * 128, 2, false, As, Bs);
  }
}

__global__ __launch_bounds__(256, 3) void gemm_out(
    const u16* __restrict__ ctx, const u16* __restrict__ WbpT,
    const float* __restrict__ bp, float* __restrict__ out) {
  __shared__ alignas(16) u16 As[12288], Bs[12288];
  const int t = blockIdx.x;                 // 384 = 8 xcd * 48
  const int w = (t & 7) * 48 + (t >> 3);    // XCD-chunked logical id
  gemm_tile<0>(ctx, WbpT, bp, out, 384, 384, 384, 768,
               (w / 6) * 128, (w % 6) * 128, 1, false, As, Bs);
}

// ---------------- causal flash attention, KVBLK=128, 4-wave blocks ----------
// grid: 768 blocks x 256 thr (heavy chunks first, global order — R1-proven).
// Block = 128 q-rows of one (b,h); wave w owns rows [cc*128 + w*32, +32).
// Per barrier-step: stage a 128-k K tile (global_load_lds, 2 chunks/thread)
// and a 32x128 V tile (reg->LDS, 2 uint4/thread, issue-early/write-late T14);
// compute as TWO serial 64-k halves (same reg footprint as KVBLK=64).
__global__ __launch_bounds__(256, 4) void attn_kernel(
    const u16* __restrict__ QK, const u16* __restrict__ VT,
    u16* __restrict__ ctx) {
  __shared__ alignas(16) u16 Ks[2][4096];       // 8KB per buffer (128k x 32hd)
  __shared__ alignas(16) u16 Vs[2][32 * 136];   // 8.5KB per buffer (padded rows)
  const int tid = threadIdx.x;
  const int w = tid >> 6, l = tid & 63;
  const int r = l & 15, g = l >> 4;
  const int idx = blockIdx.x;
  const int cc = 15 - idx / 48;                // q-chunk (128 rows), heavy first
  const int bh = idx % 48;
  const int b = bh / 12, h = bh % 12;
  const size_t tok0 = (size_t)b * 2048;
  const int q0 = cc * 128 + w * 32;            // this wave's q-strip base
  const u16* Qb = QK + (tok0 + q0) * 768 + h * 32;
  const u16* Kb = QK + tok0 * 768 + 384 + h * 32;
  const u16* Vb = VT + (size_t)(h * 32) * VLD + b * 2048;
  const float scale2 = 0.25500526474f;         // (1/sqrt(32))*log2(e)
  const float THR = 8.0f;                      // defer-max threshold (T13)
  const f32x4 fz = {0.f, 0.f, 0.f, 0.f};

  short8 qf[2];
  qf[0] = *(const short8*)&Qb[(size_t)r * 768 + 8 * g];
  qf[1] = *(const short8*)&Qb[(size_t)(16 + r) * 768 + 8 * g];

  float mrun[2] = {-3.0e38f, -3.0e38f};
  float lpart[2] = {0.f, 0.f};                 // per-lane partial row sums
  f32x4 o[2][2] = {};                          // o[di][mi]: d=16di+4g+jj, q=16mi+r
  const int nt = cc + 1;                       // 128-k tiles in this chunk

  // staging roles (fixed per thread; all 256 threads do K and V)
  const int krow = ((tid >> 6) << 4) + (tid & 15);   // K chunk row (0..63)
  const int kcol = ((tid >> 4) & 3) * 8;             // K chunk col
  const int vd   = tid >> 3;                          // V row d (0..31)
  const int vkc  = (tid & 7) * 8;                     // V col chunk (0..56)

  uint4 vreg0, vreg1;
  auto stageK = [&](int t, int buf) {
    gload_lds16(&Kb[(size_t)(t * 128 + krow) * 768 + kcol],      &Ks[buf][(size_t)tid * 8]);
    gload_lds16(&Kb[(size_t)(t * 128 + 64 + krow) * 768 + kcol], &Ks[buf][(size_t)(tid + 256) * 8]);
  };
  auto loadV = [&](int t) {
    vreg0 = *(const uint4*)&Vb[(size_t)vd * VLD + t * 128 + vkc];
    vreg1 = *(const uint4*)&Vb[(size_t)vd * VLD + t * 128 + 64 + vkc];
  };
  auto writeV = [&](int buf) {
    *(uint4*)&Vs[buf][vd * 136 + vkc]      = vreg0;
    *(uint4*)&Vs[buf][vd * 136 + 64 + vkc] = vreg1;
  };

  loadV(0); stageK(0, 0); writeV(0);
  __syncthreads();
  int cur = 0;
  for (int t = 0; t < nt; ++t) {
    const bool pf = (t + 1 < nt);
    if (pf) { loadV(t + 1); stageK(t + 1, cur ^ 1); }  // issue next tile early
    #pragma unroll
    for (int hh = 0; hh < 2; ++hh) {
      const int k0 = t * 128 + hh * 64;
      if (k0 > q0 + 31) continue;              // wave fully above this half
      // K fragments: lane holds K[k=k0+16kj+r][hd=8g..]
      short8 kf[4];
      #pragma unroll
      for (int kj = 0; kj < 4; ++kj)
        kf[kj] = *(const short8*)&Ks[cur][(hh * 256 + kj * 64 + l) * 8];
      // V^T fragments: lane holds VT[d=16di+r][k=k0+16kj+4g..+3]
      bf16x4 vf[2][4];
      #pragma unroll
      for (int di = 0; di < 2; ++di)
        #pragma unroll
        for (int kj = 0; kj < 4; ++kj)
          vf[di][kj] = *(const bf16x4*)&Vs[cur][(16 * di + r) * 136 + hh * 64 + kj * 16 + 4 * g];

      // S^T = K Q^T : lane holds S[k=k0+16kj+4g+jj][q=16mi+r]  (raw)
      f32x4 s[2][4];
      __builtin_amdgcn_s_setprio(1);
      #pragma unroll
      for (int kj = 0; kj < 4; ++kj)
        #pragma unroll
        for (int mi = 0; mi < 2; ++mi)
          s[mi][kj] = __builtin_amdgcn_mfma_f32_16x16x32_bf16(kf[kj], qf[mi], fz, 0, 0, 0);
      __builtin_amdgcn_s_setprio(0);

      if (t == nt - 1) {  // only the diagonal tile needs masking
        #pragma unroll
        for (int mi = 0; mi < 2; ++mi) {
          const int qq = q0 + mi * 16 + r;
          #pragma unroll
          for (int kj = 0; kj < 4; ++kj)
            #pragma unroll
            for (int jj = 0; jj < 4; ++jj) {
              const int kk = k0 + kj * 16 + 4 * g + jj;
              if (kk > qq) s[mi][kj][jj] = -3.0e38f;
            }
        }
      }

      #pragma unroll
      for (int mi = 0; mi < 2; ++mi) {
        const float a0 = fmaxf(fmaxf(s[mi][0][0], s[mi][0][1]), fmaxf(s[mi][0][2], s[mi][0][3]));
        const float a1 = fmaxf(fmaxf(s[mi][1][0], s[mi][1][1]), fmaxf(s[mi][1][2], s[mi][1][3]));
        const float a2 = fmaxf(fmaxf(s[mi][2][0], s[mi][2][1]), fmaxf(s[mi][2][2], s[mi][2][3]));
        const float a3 = fmaxf(fmaxf(s[mi][3][0], s[mi][3][1]), fmaxf(s[mi][3][2], s[mi][3][3]));
        const float lmxs = fmaxf(fmaxf(a0, a1), fmaxf(a2, a3)) * scale2;
        if (__any(lmxs > mrun[mi] + THR)) {    // rare: reduce + per-lane rescale
          float mx = lmxs;
          mx = fmaxf(mx, __shfl_xor(mx, 16));
          mx = fmaxf(mx, __shfl_xor(mx, 32));
          const float mnew = fmaxf(mrun[mi], mx);
          const float al = exp2v(mrun[mi] - mnew);
          mrun[mi] = mnew;
          lpart[mi] *= al;
          o[0][mi] *= al;                      // q lane-indexed: plain multiply
          o[1][mi] *= al;
        }
        #pragma unroll
        for (int kj = 0; kj < 4; ++kj)
          #pragma unroll
          for (int jj = 0; jj < 4; ++jj) {
            const float pv = exp2v(fmaf(s[mi][kj][jj], scale2, -mrun[mi]));
            s[mi][kj][jj] = pv;
            lpart[mi] += pv;
          }
      }

      // PV in-register: O^T[d][q] += V^T[d][k] * P^T[k][q]
      __builtin_amdgcn_s_setprio(1);
      #pragma unroll
      for (int kj = 0; kj < 4; ++kj) {
        const bf16x4 pf0 = pack4(s[0][kj]);
        const bf16x4 pf1 = pack4(s[1][kj]);
        #pragma unroll
        for (int di = 0; di < 2; ++di) {
          o[di][0] = mfma16bf(vf[di][kj], pf0, o[di][0]);
          o[di][1] = mfma16bf(vf[di][kj], pf1, o[di][1]);
        }
      }
      __builtin_amdgcn_s_setprio(0);
    }
    if (pf) writeV(cur ^ 1);                   // land V after compute (T14)
    __syncthreads();
    cur ^= 1;
  }

  // epilogue: per-wave l reduction (2 shfl) + direct store (no merge)
  #pragma unroll
  for (int mi = 0; mi < 2; ++mi) {
    float lr = lpart[mi];
    lr += __shfl_xor(lr, 16);
    lr += __shfl_xor(lr, 32);
    const float li = 1.0f / lr;
    const size_t row = tok0 + q0 + mi * 16 + r;
    #pragma unroll
    for (int di = 0; di < 2; ++di) {
      const u32 d0 = cvtpk_bf16(o[di][mi][0] * li, o[di][mi][1] * li);
      const u32 d1 = cvtpk_bf16(o[di][mi][2] * li, o[di][mi][3] * li);
      *(uint2*)&ctx[row * 384 + h * 32 + di * 16 + 4 * g] = make_uint2(d0, d1);
    }
  }
}

// ---------------------------------------------------------------------------
extern "C" void kernel_launch(void* const* d_in, const int* in_sizes, int n_in,
                              void* d_out, int out_size, void* d_ws, size_t ws_size,
                              hipStream_t stream) {
  const float* x      = (const float*)d_in[0];
  const float* W_attn = (const float*)d_in[1];
  const float* b_attn = (const float*)d_in[2];
  const float* P_q    = (const float*)d_in[3];
  const float* P_k    = (const float*)d_in[4];
  const float* P_v    = (const float*)d_in[5];
  const float* W_back = (const float*)d_in[6];
  const float* W_proj = (const float*)d_in[7];
  const float* b_proj = (const float*)d_in[8];

  char* ws = (char*)d_ws;
  u16*   x_bf   = (u16*)(ws);               // 8192x768 bf16
  u16*   ctx    = (u16*)(ws);               // 8192x384, aliases dead x_bf
  u16*   Wat_bf = (u16*)(ws + 12582912);    // 768x2304
  u16*   PT     = (u16*)(ws + 16121856);    // 1152x768
  u16*   Wbk_bf = (u16*)(ws + 17891328);    // 384x768
  u16*   WprT   = (u16*)(ws + 18481152);    // 768x768
  u16*   WcT    = (u16*)(ws + 19660800);    // 1152x768
  u16*   WbpT   = (u16*)(ws + 21430272);    // 768x384
  float* bc     = (float*)(ws + 22020096);  // 1152
  u16*   QKbuf  = (u16*)d_out;                          // 8192x768 (dead before gemm_out)
  u16*   VTbuf  = (u16*)((char*)d_out + 12582912);      // 384xVLD (dead before gemm_out)
  float* out    = (float*)d_out;

  prep_w<<<3456, 256, 0, stream>>>(W_attn, W_back, P_q, P_k, P_v, W_proj,
                                   Wat_bf, Wbk_bf, PT, WprT);
  gemm_prep<<<6224, 256, 0, stream>>>(PT, Wat_bf, WprT, Wbk_bf, b_attn, x,
                                      WcT, WbpT, bc, x_bf);
  gemm_qkvt<<<576, 256, 0, stream>>>(x_bf, WcT, bc, QKbuf, VTbuf);
  attn_kernel<<<768, 256, 0, stream>>>(QKbuf, VTbuf, ctx);
  gemm_out<<<384, 256, 0, stream>>>(ctx, WbpT, b_proj, out);
}

// Round 14
// 118.047 us; speedup vs baseline: 1.0395x; 1.0035x over previous
//
#include <hip/hip_runtime.h>
#include <math.h>

// ---------------------------------------------------------------------------
// PatchedCausalSelfAttention  B=4 S=2048 D=768 DC=384 H=12 HD=32
//   prep_w   : weight casts + transposes (3456 blocks)   (1 launch)
//   gemm_prep: FUSED: blocks 0-79 WcT/WbpT/bc GEMM jobs (BK=64: these are
//              LATENCY-bound at 0.3 blocks/CU — duration = per-block serial
//              step count x ~1800cy, so halving steps ~halves time; R7
//              proved the BK=64 pipelined tile correct and neutral at load),
//              blocks 80-6223 x fp32->bf16 cast filling the idle CUs.
//   gemm_qkvt: QKbuf[8192][768], VT[384][8320-pad]; BK=32 depth-3 (at-load
//              floor, 40.4us across 11 variants — do not re-tune).
//   attn     : ctx[8192][384] flash-causal, KVBLK=128.
//   gemm_out : out[8192][768] fp32; BK=64 (1.5 blocks/CU, latency-bound:
//              12 -> 6 steps).
// XCD-chunked mapping (T1) on qkvt/out. attn: R1-proven global heavy-first
// order (R2's bh-major XCD map aliased same-size blocks onto one CU).
// ---------------------------------------------------------------------------

typedef unsigned short u16;
typedef unsigned int   u32;

#define VLD 8320   // VT leading dimension (elements)

using short8 = __attribute__((ext_vector_type(8))) short;  // 8 bf16
using bf16x4 = __attribute__((ext_vector_type(4))) short;  // 4 bf16
using f32x4  = __attribute__((ext_vector_type(4))) float;

__device__ __forceinline__ u16 f2bf(float f) {
  u32 u = __builtin_bit_cast(u32, f);
  u = (u + 0x7fffu + ((u >> 16) & 1u)) >> 16;   // RNE
  return (u16)u;
}

__device__ __forceinline__ float b2f(u16 b) {
  return __builtin_bit_cast(float, (u32)b << 16);
}

__device__ __forceinline__ u32 cvtpk_bf16(float lo, float hi) {
  u32 d;
  asm("v_cvt_pk_bf16_f32 %0, %1, %2" : "=v"(d) : "v"(lo), "v"(hi));
  return d;
}

__device__ __forceinline__ bf16x4 pack4(const f32x4 v) {
  union { u32 u[2]; bf16x4 s; } c;
  c.u[0] = cvtpk_bf16(v[0], v[1]);
  c.u[1] = cvtpk_bf16(v[2], v[3]);
  return c.s;
}

// single-instruction 2^x (v_exp_f32). Large-negative inputs underflow to 0.
__device__ __forceinline__ float exp2v(float x) {
  return __builtin_amdgcn_exp2f(x);
}

__device__ __forceinline__ f32x4 mfma16bf(bf16x4 a, bf16x4 b, f32x4 c) {
#if __has_builtin(__builtin_amdgcn_mfma_f32_16x16x16bf16_1k)
  return __builtin_amdgcn_mfma_f32_16x16x16bf16_1k(a, b, c, 0, 0, 0);
#elif __has_builtin(__builtin_amdgcn_mfma_f32_16x16x16_bf16)
  return __builtin_amdgcn_mfma_f32_16x16x16_bf16(a, b, c, 0, 0, 0);
#else
  f32x4 d;  // non-volatile: scheduler may interleave with surrounding VALU
  asm("v_mfma_f32_16x16x16_bf16 %0, %1, %2, %3"
      : "=v"(d) : "v"(a), "v"(b), "v"(c));
  return d;
#endif
}

__device__ __forceinline__ void gload_lds16(const void* g, void* l) {
  __builtin_amdgcn_global_load_lds((__attribute__((address_space(1))) u32*)g,
                                   (__attribute__((address_space(3))) u32*)l,
                                   16, 0, 0);
}

// LDS byte offset of a pointer known to be in LDS (generic -> AS3 -> int).
__device__ __forceinline__ u32 lds_u32(const void* p) {
  return (u32)(size_t)(const __attribute__((address_space(3))) char*)p;
}

// ---------------- weight prep: casts + transposes ---------------------------
__global__ __launch_bounds__(256) void prep_w(
    const float* __restrict__ Wa, const float* __restrict__ Wb,
    const float* __restrict__ Pq, const float* __restrict__ Pk,
    const float* __restrict__ Pv, const float* __restrict__ Wp,
    u16* __restrict__ Wat_bf, u16* __restrict__ Wbk_bf,
    u16* __restrict__ PT, u16* __restrict__ WprT) {
  __shared__ float t[32][33];
  const int blk = blockIdx.x, tid = threadIdx.x;
  if (blk < 2016) {  // vectorized weight casts (x4 floats per thread)
    const float* src; u16* dst; int i;
    if (blk < 1728) { src = Wa; dst = Wat_bf; i = blk * 256 + tid; }
    else            { src = Wb; dst = Wbk_bf; i = (blk - 1728) * 256 + tid; }
    const float4 v = ((const float4*)src)[i];
    ((ushort4*)dst)[i] = make_ushort4(f2bf(v.x), f2bf(v.y), f2bf(v.z), f2bf(v.w));
    return;
  }
  // transpose+cast 32x32 tiles
  const int b2 = blk - 2016;   // 0..1439
  const float* src; u16* dst; int C, R, bx, by;
  if (b2 < 288)      { src = Pq; dst = PT;             R = 768; C = 384; bx = b2 % 12; by = b2 / 12; }
  else if (b2 < 576) { src = Pk; dst = PT + 384 * 768; R = 768; C = 384; int t2 = b2 - 288; bx = t2 % 12; by = t2 / 12; }
  else if (b2 < 864) { src = Pv; dst = PT + 768 * 768; R = 768; C = 384; int t2 = b2 - 576; bx = t2 % 12; by = t2 / 12; }
  else               { src = Wp; dst = WprT;           R = 768; C = 768; int t2 = b2 - 864; bx = t2 % 24; by = t2 / 24; }
  const int c0 = bx * 32, r0 = by * 32, tx = tid & 31, ty = tid >> 5;
  for (int i = ty; i < 32; i += 8)
    t[i][tx] = src[(size_t)(r0 + i) * C + c0 + tx];
  __syncthreads();
  for (int i = ty; i < 32; i += 8)
    dst[(size_t)(c0 + i) * R + r0 + tx] = f2bf(t[tx][i]);
}

// ---------------- bf16 MFMA GEMM tile 128x128, BK=32 depth-3 (at-load) ------
template<int OBF16>
__device__ __forceinline__ void gemm_tile(
    const u16* __restrict__ A, const u16* __restrict__ BT,
    const float* __restrict__ bias, void* __restrict__ Cv,
    int K, int lda, int ldb, int ldc, int m0, int n0, int biasmode, bool slab,
    u16* As, u16* Bs) {
  const int tid = threadIdx.x;
  const int l = tid & 63, w = tid >> 6;
  const int r = l & 15, g = l >> 4;
  const int koff = slab ? (m0 / 384) * 768 : 0;
  const u16* Ap = A + ((size_t)m0 + w * 16 + r) * lda + g * 8;
  const u16* Bp = BT + ((size_t)n0 + w * 16 + r) * ldb + koff + g * 8;
  f32x4 acc[4][4] = {};
  const int wma = (w >> 1) * 4, wnb = (w & 1) * 4;
  const int nk = K >> 5;   // >= 12 for all call sites

  const u32 abase = lds_u32(As) + (u32)(wma * 1024 + l * 16);
  const u32 bbase = lds_u32(Bs) + (u32)(wnb * 1024 + l * 16);

  auto stage = [&](int kt, int buf) {
    const int o = buf * 4096;
    gload_lds16(Ap + kt,                    &As[o + (size_t)tid * 8]);
    gload_lds16(Ap + kt + (size_t)64 * lda, &As[o + 2048 + (size_t)tid * 8]);
    gload_lds16(Bp + kt,                    &Bs[o + (size_t)tid * 8]);
    gload_lds16(Bp + kt + (size_t)64 * ldb, &Bs[o + 2048 + (size_t)tid * 8]);
  };

  stage(0, 0);
  stage(32, 1);
  stage(64, 2);                     // 12 loads in flight
  int cur = 0;
  for (int t = 0; t < nk; ++t) {
    if (t + 2 < nk)      asm volatile("s_waitcnt vmcnt(8)" ::: "memory");
    else if (t + 1 < nk) asm volatile("s_waitcnt vmcnt(4)" ::: "memory");
    else                 asm volatile("s_waitcnt vmcnt(0)" ::: "memory");
    __builtin_amdgcn_s_barrier();   // tile t resident in buf cur (all waves)
    __builtin_amdgcn_sched_barrier(0);
    const u32 off = (u32)(cur * 8192);  // buffer stride 8KB
    short8 af[4], bfr[4];
    #pragma unroll
    for (int i = 0; i < 4; ++i) {
      asm volatile("ds_read_b128 %0, %1" : "=v"(af[i])  : "v"(abase + off + 1024u * i));
      asm volatile("ds_read_b128 %0, %1" : "=v"(bfr[i]) : "v"(bbase + off + 1024u * i));
    }
    asm volatile("s_waitcnt lgkmcnt(0)" ::: "memory");
    __builtin_amdgcn_sched_barrier(0);  // rule 18: nothing hoists above the wait
    __builtin_amdgcn_s_barrier();       // all waves' reads done -> buf cur free
    __builtin_amdgcn_sched_barrier(0);
    if (t + 3 < nk) stage((t + 3) << 5, cur);  // refill freed buffer, in flight
    #pragma unroll
    for (int mi = 0; mi < 4; ++mi)
      #pragma unroll
      for (int ni = 0; ni < 4; ++ni)
        acc[mi][ni] = __builtin_amdgcn_mfma_f32_16x16x32_bf16(af[mi], bfr[ni],
                                                              acc[mi][ni], 0, 0, 0);
    cur = (cur == 2) ? 0 : cur + 1;
  }

  const int row0 = m0 + (w >> 1) * 64, col0 = n0 + (w & 1) * 64;
  #pragma unroll
  for (int ni = 0; ni < 4; ++ni) {
    const int col = col0 + ni * 16 + r;
    const float bvc = (biasmode == 1) ? bias[col] : 0.f;
    #pragma unroll
    for (int mi = 0; mi < 4; ++mi)
      #pragma unroll
      for (int j = 0; j < 4; ++j) {
        const int row = row0 + mi * 16 + 4 * g + j;
        float bv = bvc;
        if (biasmode == 2) bv = bias[row];
        const float v = acc[mi][ni][j] + bv;
        if (OBF16) ((u16*)Cv)[(size_t)row * ldc + col] = f2bf(v);
        else       ((float*)Cv)[(size_t)row * ldc + col] = v;
      }
  }
}

// ---------------- bf16 MFMA GEMM tile 128x128, BK=64 (latency-bound) --------
// R7-verified. Double-buffered 64KB LDS. Counted vmcnt(8); 32 MFMA/wave/step
// in two khalf clusters. Half the barrier-steps of BK=32 -> for kernels at
// <2 blocks/CU (duration = per-block serial time) this ~halves duration.
template<int OBF16>
__device__ __forceinline__ void gemm_tile64(
    const u16* __restrict__ A, const u16* __restrict__ BT,
    const float* __restrict__ bias, void* __restrict__ Cv,
    int K, int lda, int ldb, int ldc, int m0, int n0, int biasmode, bool slab,
    u16* As, u16* Bs) {
  const int tid = threadIdx.x;
  const int l = tid & 63, w = tid >> 6;
  const int r = l & 15, g = l >> 4;
  const int koff = slab ? (m0 / 384) * 768 : 0;
  const u16* Ap = A + ((size_t)m0 + w * 16 + r) * lda + g * 8;
  const u16* Bp = BT + ((size_t)n0 + w * 16 + r) * ldb + koff + g * 8;
  f32x4 acc[4][4] = {};
  const int wma = (w >> 1) * 4, wnb = (w & 1) * 4;
  const int nk = K >> 6;   // BK=64; K in {384,768} -> nk in {6,12}

  const u32 abase = lds_u32(As) + (u32)(wma * 1024 + l * 16);
  const u32 bbase = lds_u32(Bs) + (u32)(wnb * 1024 + l * 16);

  // buffer = 16KB; khalf stride 8KB. Stage 8 chunks/thread per tile.
  auto stage = [&](int kt, int buf) {
    const int o = buf * 8192;                    // elems
    gload_lds16(Ap + kt,                         &As[o        + (size_t)tid * 8]);
    gload_lds16(Ap + kt      + (size_t)64 * lda, &As[o + 2048 + (size_t)tid * 8]);
    gload_lds16(Ap + kt + 32,                    &As[o + 4096 + (size_t)tid * 8]);
    gload_lds16(Ap + kt + 32 + (size_t)64 * lda, &As[o + 6144 + (size_t)tid * 8]);
    gload_lds16(Bp + kt,                         &Bs[o        + (size_t)tid * 8]);
    gload_lds16(Bp + kt      + (size_t)64 * ldb, &Bs[o + 2048 + (size_t)tid * 8]);
    gload_lds16(Bp + kt + 32,                    &Bs[o + 4096 + (size_t)tid * 8]);
    gload_lds16(Bp + kt + 32 + (size_t)64 * ldb, &Bs[o + 6144 + (size_t)tid * 8]);
  };

  stage(0, 0);
  stage(64, 1);                     // 16 loads in flight
  int cur = 0;
  for (int t = 0; t < nk; ++t) {
    if (t + 1 < nk) asm volatile("s_waitcnt vmcnt(8)" ::: "memory");
    else            asm volatile("s_waitcnt vmcnt(0)" ::: "memory");
    __builtin_amdgcn_s_barrier();   // tile t resident in buf cur (all waves)
    __builtin_amdgcn_sched_barrier(0);
    const u32 off = (u32)cur << 14; // cur * 16384 bytes
    short8 a0[4], b0[4], a1[4], b1[4];
    #pragma unroll
    for (int i = 0; i < 4; ++i) {
      asm volatile("ds_read_b128 %0, %1" : "=v"(a0[i]) : "v"(abase + off + 1024u * i));
      asm volatile("ds_read_b128 %0, %1" : "=v"(b0[i]) : "v"(bbase + off + 1024u * i));
    }
    #pragma unroll
    for (int i = 0; i < 4; ++i) {
      asm volatile("ds_read_b128 %0, %1" : "=v"(a1[i]) : "v"(abase + off + 8192u + 1024u * i));
      asm volatile("ds_read_b128 %0, %1" : "=v"(b1[i]) : "v"(bbase + off + 8192u + 1024u * i));
    }
    asm volatile("s_waitcnt lgkmcnt(8)" ::: "memory");
    __builtin_amdgcn_sched_barrier(0);  // rule 18
    #pragma unroll
    for (int mi = 0; mi < 4; ++mi)
      #pragma unroll
      for (int ni = 0; ni < 4; ++ni)
        acc[mi][ni] = __builtin_amdgcn_mfma_f32_16x16x32_bf16(a0[mi], b0[ni],
                                                              acc[mi][ni], 0, 0, 0);
    asm volatile("s_waitcnt lgkmcnt(0)" ::: "memory");
    __builtin_amdgcn_sched_barrier(0);  // rule 18
    __builtin_amdgcn_s_barrier();       // all waves' reads done -> buf cur free
    __builtin_amdgcn_sched_barrier(0);
    if (t + 2 < nk) stage((t + 2) << 6, cur);  // refill freed buffer, in flight
    #pragma unroll
    for (int mi = 0; mi < 4; ++mi)
      #pragma unroll
      for (int ni = 0; ni < 4; ++ni)
        acc[mi][ni] = __builtin_amdgcn_mfma_f32_16x16x32_bf16(a1[mi], b1[ni],
                                                              acc[mi][ni], 0, 0, 0);
    cur ^= 1;
  }

  const int row0 = m0 + (w >> 1) * 64, col0 = n0 + (w & 1) * 64;
  #pragma unroll
  for (int ni = 0; ni < 4; ++ni) {
    const int col = col0 + ni * 16 + r;
    const float bvc = (biasmode == 1) ? bias[col] : 0.f;
    #pragma unroll
    for (int mi = 0; mi < 4; ++mi)
      #pragma unroll
      for (int j = 0; j < 4; ++j) {
        const int row = row0 + mi * 16 + 4 * g + j;
        float bv = bvc;
        if (biasmode == 2) bv = bias[row];
        const float v = acc[mi][ni][j] + bv;
        if (OBF16) ((u16*)Cv)[(size_t)row * ldc + col] = f2bf(v);
        else       ((float*)Cv)[(size_t)row * ldc + col] = v;
      }
  }
}

// FUSED prep2: blocks [0,54) WcT; [54,72) WbpT; [72,80) bc; [80,6224) x-cast.
// GEMM jobs (BK=64, 12 steps) at low blockIdx dispatch first; cast blocks
// fill the idle CUs.
__global__ __launch_bounds__(256, 2) void gemm_prep(
    const u16* __restrict__ PT, const u16* __restrict__ Wat,
    const u16* __restrict__ WprT, const u16* __restrict__ Wbk,
    const float* __restrict__ ba, const float* __restrict__ x,
    u16* __restrict__ WcT, u16* __restrict__ WbpT, float* __restrict__ bc,
    u16* __restrict__ x_bf) {
  __shared__ alignas(16) u16 As[16384], Bs[16384];
  const int t = blockIdx.x;
  if (t >= 80) {  // x fp32->bf16 cast (independent of the GEMM jobs)
    const int i = (t - 80) * 256 + threadIdx.x;
    const float4 v = ((const float4*)x)[i];
    ((ushort4*)x_bf)[i] = make_ushort4(f2bf(v.x), f2bf(v.y), f2bf(v.z), f2bf(v.w));
    return;
  }
  if (t < 54) {
    gemm_tile64<1>(PT, Wat, nullptr, WcT, 768, 768, 2304, 768,
                   (t % 9) * 128, (t / 9) * 128, 0, true, As, Bs);
  } else if (t < 72) {
    const int t2 = t - 54;
    gemm_tile64<1>(WprT, Wbk, nullptr, WbpT, 768, 768, 768, 384,
                   (t2 % 6) * 128, (t2 / 6) * 128, 0, false, As, Bs);
  } else {
    const int c = (t - 72) * 144 + threadIdx.x;
    if (threadIdx.x < 144 && c < 1152) {
      const int slab = c / 384;
      const float* bs = ba + slab * 768;
      const u16* row = PT + (size_t)c * 768;
      float s = 0.f;
      for (int jj = 0; jj < 96; ++jj) {
        const short8 v = *(const short8*)&row[jj * 8];
        #pragma unroll
        for (int e = 0; e < 8; ++e)
          s = fmaf(bs[jj * 8 + e], b2f((u16)v[e]), s);
      }
      bc[c] = s;
    }
  }
}

// main GEMMs, XCD-chunked: logical w groups the 9 jobs reading one 128-token
// x_bf strip (6 QK col-panels + 3 VT row-panels); xcd = t%8 round-robin.
__global__ __launch_bounds__(256, 3) void gemm_qkvt(
    const u16* __restrict__ x_bf, const u16* __restrict__ WcT,
    const float* __restrict__ bc, u16* __restrict__ QKbuf, u16* __restrict__ VTbuf) {
  __shared__ alignas(16) u16 As[12288], Bs[12288];
  const int t = blockIdx.x;                 // 576 = 8 xcd * 72
  const int w = (t & 7) * 72 + (t >> 3);    // XCD-chunked logical id
  const int s = w / 9, j = w % 9;           // token strip, sub-job
  if (j < 6) {
    gemm_tile<1>(x_bf, WcT, bc, QKbuf, 768, 768, 768, 768,
                 s * 128, j * 128, 1, false, As, Bs);
  } else {
    gemm_tile<1>(WcT + (size_t)768 * 768, x_bf, bc + 768, VTbuf, 768, 768, 768, VLD,
                 (j - 6) * 128, s * 128, 2, false, As, Bs);
  }
}

__global__ __launch_bounds__(256, 2) void gemm_out(
    const u16* __restrict__ ctx, const u16* __restrict__ WbpT,
    const float* __restrict__ bp, float* __restrict__ out) {
  __shared__ alignas(16) u16 As[16384], Bs[16384];
  const int t = blockIdx.x;                 // 384 = 8 xcd * 48
  const int w = (t & 7) * 48 + (t >> 3);    // XCD-chunked logical id
  gemm_tile64<0>(ctx, WbpT, bp, out, 384, 384, 384, 768,
                 (w / 6) * 128, (w % 6) * 128, 1, false, As, Bs);
}

// ---------------- causal flash attention, KVBLK=128, 4-wave blocks ----------
// grid: 768 blocks x 256 thr (heavy chunks first, global order — R1-proven).
// Block = 128 q-rows of one (b,h); wave w owns rows [cc*128 + w*32, +32).
// Per barrier-step: stage a 128-k K tile (global_load_lds, 2 chunks/thread)
// and a 32x128 V tile (reg->LDS, 2 uint4/thread, issue-early/write-late T14);
// compute as TWO serial 64-k halves (same reg footprint as KVBLK=64).
__global__ __launch_bounds__(256, 4) void attn_kernel(
    const u16* __restrict__ QK, const u16* __restrict__ VT,
    u16* __restrict__ ctx) {
  __shared__ alignas(16) u16 Ks[2][4096];       // 8KB per buffer (128k x 32hd)
  __shared__ alignas(16) u16 Vs[2][32 * 136];   // 8.5KB per buffer (padded rows)
  const int tid = threadIdx.x;
  const int w = tid >> 6, l = tid & 63;
  const int r = l & 15, g = l >> 4;
  const int idx = blockIdx.x;
  const int cc = 15 - idx / 48;                // q-chunk (128 rows), heavy first
  const int bh = idx % 48;
  const int b = bh / 12, h = bh % 12;
  const size_t tok0 = (size_t)b * 2048;
  const int q0 = cc * 128 + w * 32;            // this wave's q-strip base
  const u16* Qb = QK + (tok0 + q0) * 768 + h * 32;
  const u16* Kb = QK + tok0 * 768 + 384 + h * 32;
  const u16* Vb = VT + (size_t)(h * 32) * VLD + b * 2048;
  const float scale2 = 0.25500526474f;         // (1/sqrt(32))*log2(e)
  const float THR = 8.0f;                      // defer-max threshold (T13)
  const f32x4 fz = {0.f, 0.f, 0.f, 0.f};

  short8 qf[2];
  qf[0] = *(const short8*)&Qb[(size_t)r * 768 + 8 * g];
  qf[1] = *(const short8*)&Qb[(size_t)(16 + r) * 768 + 8 * g];

  float mrun[2] = {-3.0e38f, -3.0e38f};
  float lpart[2] = {0.f, 0.f};                 // per-lane partial row sums
  f32x4 o[2][2] = {};                          // o[di][mi]: d=16di+4g+jj, q=16mi+r
  const int nt = cc + 1;                       // 128-k tiles in this chunk

  // staging roles (fixed per thread; all 256 threads do K and V)
  const int krow = ((tid >> 6) << 4) + (tid & 15);   // K chunk row (0..63)
  const int kcol = ((tid >> 4) & 3) * 8;             // K chunk col
  const int vd   = tid >> 3;                          // V row d (0..31)
  const int vkc  = (tid & 7) * 8;                     // V col chunk (0..56)

  uint4 vreg0, vreg1;
  auto stageK = [&](int t, int buf) {
    gload_lds16(&Kb[(size_t)(t * 128 + krow) * 768 + kcol],      &Ks[buf][(size_t)tid * 8]);
    gload_lds16(&Kb[(size_t)(t * 128 + 64 + krow) * 768 + kcol], &Ks[buf][(size_t)(tid + 256) * 8]);
  };
  auto loadV = [&](int t) {
    vreg0 = *(const uint4*)&Vb[(size_t)vd * VLD + t * 128 + vkc];
    vreg1 = *(const uint4*)&Vb[(size_t)vd * VLD + t * 128 + 64 + vkc];
  };
  auto writeV = [&](int buf) {
    *(uint4*)&Vs[buf][vd * 136 + vkc]      = vreg0;
    *(uint4*)&Vs[buf][vd * 136 + 64 + vkc] = vreg1;
  };

  loadV(0); stageK(0, 0); writeV(0);
  __syncthreads();
  int cur = 0;
  for (int t = 0; t < nt; ++t) {
    const bool pf = (t + 1 < nt);
    if (pf) { loadV(t + 1); stageK(t + 1, cur ^ 1); }  // issue next tile early
    #pragma unroll
    for (int hh = 0; hh < 2; ++hh) {
      const int k0 = t * 128 + hh * 64;
      if (k0 > q0 + 31) continue;              // wave fully above this half
      // K fragments: lane holds K[k=k0+16kj+r][hd=8g..]
      short8 kf[4];
      #pragma unroll
      for (int kj = 0; kj < 4; ++kj)
        kf[kj] = *(const short8*)&Ks[cur][(hh * 256 + kj * 64 + l) * 8];
      // V^T fragments: lane holds VT[d=16di+r][k=k0+16kj+4g..+3]
      bf16x4 vf[2][4];
      #pragma unroll
      for (int di = 0; di < 2; ++di)
        #pragma unroll
        for (int kj = 0; kj < 4; ++kj)
          vf[di][kj] = *(const bf16x4*)&Vs[cur][(16 * di + r) * 136 + hh * 64 + kj * 16 + 4 * g];

      // S^T = K Q^T : lane holds S[k=k0+16kj+4g+jj][q=16mi+r]  (raw)
      f32x4 s[2][4];
      __builtin_amdgcn_s_setprio(1);
      #pragma unroll
      for (int kj = 0; kj < 4; ++kj)
        #pragma unroll
        for (int mi = 0; mi < 2; ++mi)
          s[mi][kj] = __builtin_amdgcn_mfma_f32_16x16x32_bf16(kf[kj], qf[mi], fz, 0, 0, 0);
      __builtin_amdgcn_s_setprio(0);

      if (t == nt - 1) {  // only the diagonal tile needs masking
        #pragma unroll
        for (int mi = 0; mi < 2; ++mi) {
          const int qq = q0 + mi * 16 + r;
          #pragma unroll
          for (int kj = 0; kj < 4; ++kj)
            #pragma unroll
            for (int jj = 0; jj < 4; ++jj) {
              const int kk = k0 + kj * 16 + 4 * g + jj;
              if (kk > qq) s[mi][kj][jj] = -3.0e38f;
            }
        }
      }

      #pragma unroll
      for (int mi = 0; mi < 2; ++mi) {
        const float a0 = fmaxf(fmaxf(s[mi][0][0], s[mi][0][1]), fmaxf(s[mi][0][2], s[mi][0][3]));
        const float a1 = fmaxf(fmaxf(s[mi][1][0], s[mi][1][1]), fmaxf(s[mi][1][2], s[mi][1][3]));
        const float a2 = fmaxf(fmaxf(s[mi][2][0], s[mi][2][1]), fmaxf(s[mi][2][2], s[mi][2][3]));
        const float a3 = fmaxf(fmaxf(s[mi][3][0], s[mi][3][1]), fmaxf(s[mi][3][2], s[mi][3][3]));
        const float lmxs = fmaxf(fmaxf(a0, a1), fmaxf(a2, a3)) * scale2;
        if (__any(lmxs > mrun[mi] + THR)) {    // rare: reduce + per-lane rescale
          float mx = lmxs;
          mx = fmaxf(mx, __shfl_xor(mx, 16));
          mx = fmaxf(mx, __shfl_xor(mx, 32));
          const float mnew = fmaxf(mrun[mi], mx);
          const float al = exp2v(mrun[mi] - mnew);
          mrun[mi] = mnew;
          lpart[mi] *= al;
          o[0][mi] *= al;                      // q lane-indexed: plain multiply
          o[1][mi] *= al;
        }
        #pragma unroll
        for (int kj = 0; kj < 4; ++kj)
          #pragma unroll
          for (int jj = 0; jj < 4; ++jj) {
            const float pv = exp2v(fmaf(s[mi][kj][jj], scale2, -mrun[mi]));
            s[mi][kj][jj] = pv;
            lpart[mi] += pv;
          }
      }

      // PV in-register: O^T[d][q] += V^T[d][k] * P^T[k][q]
      __builtin_amdgcn_s_setprio(1);
      #pragma unroll
      for (int kj = 0; kj < 4; ++kj) {
        const bf16x4 pf0 = pack4(s[0][kj]);
        const bf16x4 pf1 = pack4(s[1][kj]);
        #pragma unroll
        for (int di = 0; di < 2; ++di) {
          o[di][0] = mfma16bf(vf[di][kj], pf0, o[di][0]);
          o[di][1] = mfma16bf(vf[di][kj], pf1, o[di][1]);
        }
      }
      __builtin_amdgcn_s_setprio(0);
    }
    if (pf) writeV(cur ^ 1);                   // land V after compute (T14)
    __syncthreads();
    cur ^= 1;
  }

  // epilogue: per-wave l reduction (2 shfl) + direct store (no merge)
  #pragma unroll
  for (int mi = 0; mi < 2; ++mi) {
    float lr = lpart[mi];
    lr += __shfl_xor(lr, 16);
    lr += __shfl_xor(lr, 32);
    const float li = 1.0f / lr;
    const size_t row = tok0 + q0 + mi * 16 + r;
    #pragma unroll
    for (int di = 0; di < 2; ++di) {
      const u32 d0 = cvtpk_bf16(o[di][mi][0] * li, o[di][mi][1] * li);
      const u32 d1 = cvtpk_bf16(o[di][mi][2] * li, o[di][mi][3] * li);
      *(uint2*)&ctx[row * 384 + h * 32 + di * 16 + 4 * g] = make_uint2(d0, d1);
    }
  }
}

// ---------------------------------------------------------------------------
extern "C" void kernel_launch(void* const* d_in, const int* in_sizes, int n_in,
                              void* d_out, int out_size, void* d_ws, size_t ws_size,
                              hipStream_t stream) {
  const float* x      = (const float*)d_in[0];
  const float* W_attn = (const float*)d_in[1];
  const float* b_attn = (const float*)d_in[2];
  const float* P_q    = (const float*)d_in[3];
  const float* P_k    = (const float*)d_in[4];
  const float* P_v    = (const float*)d_in[5];
  const float* W_back = (const float*)d_in[6];
  const float* W_proj = (const float*)d_in[7];
  const float* b_proj = (const float*)d_in[8];

  char* ws = (char*)d_ws;
  u16*   x_bf   = (u16*)(ws);               // 8192x768 bf16
  u16*   ctx    = (u16*)(ws);               // 8192x384, aliases dead x_bf
  u16*   Wat_bf = (u16*)(ws + 12582912);    // 768x2304
  u16*   PT     = (u16*)(ws + 16121856);    // 1152x768
  u16*   Wbk_bf = (u16*)(ws + 17891328);    // 384x768
  u16*   WprT   = (u16*)(ws + 18481152);    // 768x768
  u16*   WcT    = (u16*)(ws + 19660800);    // 1152x768
  u16*   WbpT   = (u16*)(ws + 21430272);    // 768x384
  float* bc     = (float*)(ws + 22020096);  // 1152
  u16*   QKbuf  = (u16*)d_out;                          // 8192x768 (dead before gemm_out)
  u16*   VTbuf  = (u16*)((char*)d_out + 12582912);      // 384xVLD (dead before gemm_out)
  float* out    = (float*)d_out;

  prep_w<<<3456, 256, 0, stream>>>(W_attn, W_back, P_q, P_k, P_v, W_proj,
                                   Wat_bf, Wbk_bf, PT, WprT);
  gemm_prep<<<6224, 256, 0, stream>>>(PT, Wat_bf, WprT, Wbk_bf, b_attn, x,
                                      WcT, WbpT, bc, x_bf);
  gemm_qkvt<<<576, 256, 0, stream>>>(x_bf, WcT, bc, QKbuf, VTbuf);
  attn_kernel<<<768, 256, 0, stream>>>(QKbuf, VTbuf, ctx);
  gemm_out<<<384, 256, 0, stream>>>(ctx, WbpT, b_proj, out);
}

// Round 16
// 118.019 us; speedup vs baseline: 1.0398x; 1.0002x over previous
//
#include <hip/hip_runtime.h>
#include <math.h>

// ---------------------------------------------------------------------------
// PatchedCausalSelfAttention  B=4 S=2048 D=768 DC=384 H=12 HD=32
//   prep_w   : weight casts + transposes (3456 blocks)   (1 launch)
//   gemm_prep: FUSED: blocks 0-79 WcT/WbpT/bc GEMM jobs (BK=64: these are
//              LATENCY-bound at 0.3 blocks/CU), blocks 80-6223 x fp32->bf16
//              cast filling the idle CUs (R12 win: cast off critical path).
//   gemm_qkvt: QKbuf[8192][768], VT[384][8320-pad]; BK=32 depth-3 (at-load
//              floor, 40.4us across 11 variants — do not re-tune).
//   attn     : ctx[8192][384] flash-causal, KVBLK=128, 128 q-rows/block.
//              (R14's 64-row/6-blocks-per-CU variant FAILED verification
//              with NaN; mask/defer-max algebra rechecks clean — reverted
//              to this proven version. Do not retry without a bisection.)
//   gemm_out : out[8192][768] fp32; BK=64.
// XCD-chunked mapping (T1) on qkvt/out. attn: R1-proven global heavy-first
// order (R2's bh-major XCD map aliased same-size blocks onto one CU).
// This is the R13 configuration, measured 118.0us (session best).
// ---------------------------------------------------------------------------

typedef unsigned short u16;
typedef unsigned int   u32;

#define VLD 8320   // VT leading dimension (elements)

using short8 = __attribute__((ext_vector_type(8))) short;  // 8 bf16
using bf16x4 = __attribute__((ext_vector_type(4))) short;  // 4 bf16
using f32x4  = __attribute__((ext_vector_type(4))) float;

__device__ __forceinline__ u16 f2bf(float f) {
  u32 u = __builtin_bit_cast(u32, f);
  u = (u + 0x7fffu + ((u >> 16) & 1u)) >> 16;   // RNE
  return (u16)u;
}

__device__ __forceinline__ float b2f(u16 b) {
  return __builtin_bit_cast(float, (u32)b << 16);
}

__device__ __forceinline__ u32 cvtpk_bf16(float lo, float hi) {
  u32 d;
  asm("v_cvt_pk_bf16_f32 %0, %1, %2" : "=v"(d) : "v"(lo), "v"(hi));
  return d;
}

__device__ __forceinline__ bf16x4 pack4(const f32x4 v) {
  union { u32 u[2]; bf16x4 s; } c;
  c.u[0] = cvtpk_bf16(v[0], v[1]);
  c.u[1] = cvtpk_bf16(v[2], v[3]);
  return c.s;
}

// single-instruction 2^x (v_exp_f32). Large-negative inputs underflow to 0.
__device__ __forceinline__ float exp2v(float x) {
  return __builtin_amdgcn_exp2f(x);
}

__device__ __forceinline__ f32x4 mfma16bf(bf16x4 a, bf16x4 b, f32x4 c) {
#if __has_builtin(__builtin_amdgcn_mfma_f32_16x16x16bf16_1k)
  return __builtin_amdgcn_mfma_f32_16x16x16bf16_1k(a, b, c, 0, 0, 0);
#elif __has_builtin(__builtin_amdgcn_mfma_f32_16x16x16_bf16)
  return __builtin_amdgcn_mfma_f32_16x16x16_bf16(a, b, c, 0, 0, 0);
#else
  f32x4 d;  // non-volatile: scheduler may interleave with surrounding VALU
  asm("v_mfma_f32_16x16x16_bf16 %0, %1, %2, %3"
      : "=v"(d) : "v"(a), "v"(b), "v"(c));
  return d;
#endif
}

__device__ __forceinline__ void gload_lds16(const void* g, void* l) {
  __builtin_amdgcn_global_load_lds((__attribute__((address_space(1))) u32*)g,
                                   (__attribute__((address_space(3))) u32*)l,
                                   16, 0, 0);
}

// LDS byte offset of a pointer known to be in LDS (generic -> AS3 -> int).
__device__ __forceinline__ u32 lds_u32(const void* p) {
  return (u32)(size_t)(const __attribute__((address_space(3))) char*)p;
}

// ---------------- weight prep: casts + transposes ---------------------------
__global__ __launch_bounds__(256) void prep_w(
    const float* __restrict__ Wa, const float* __restrict__ Wb,
    const float* __restrict__ Pq, const float* __restrict__ Pk,
    const float* __restrict__ Pv, const float* __restrict__ Wp,
    u16* __restrict__ Wat_bf, u16* __restrict__ Wbk_bf,
    u16* __restrict__ PT, u16* __restrict__ WprT) {
  __shared__ float t[32][33];
  const int blk = blockIdx.x, tid = threadIdx.x;
  if (blk < 2016) {  // vectorized weight casts (x4 floats per thread)
    const float* src; u16* dst; int i;
    if (blk < 1728) { src = Wa; dst = Wat_bf; i = blk * 256 + tid; }
    else            { src = Wb; dst = Wbk_bf; i = (blk - 1728) * 256 + tid; }
    const float4 v = ((const float4*)src)[i];
    ((ushort4*)dst)[i] = make_ushort4(f2bf(v.x), f2bf(v.y), f2bf(v.z), f2bf(v.w));
    return;
  }
  // transpose+cast 32x32 tiles
  const int b2 = blk - 2016;   // 0..1439
  const float* src; u16* dst; int C, R, bx, by;
  if (b2 < 288)      { src = Pq; dst = PT;             R = 768; C = 384; bx = b2 % 12; by = b2 / 12; }
  else if (b2 < 576) { src = Pk; dst = PT + 384 * 768; R = 768; C = 384; int t2 = b2 - 288; bx = t2 % 12; by = t2 / 12; }
  else if (b2 < 864) { src = Pv; dst = PT + 768 * 768; R = 768; C = 384; int t2 = b2 - 576; bx = t2 % 12; by = t2 / 12; }
  else               { src = Wp; dst = WprT;           R = 768; C = 768; int t2 = b2 - 864; bx = t2 % 24; by = t2 / 24; }
  const int c0 = bx * 32, r0 = by * 32, tx = tid & 31, ty = tid >> 5;
  for (int i = ty; i < 32; i += 8)
    t[i][tx] = src[(size_t)(r0 + i) * C + c0 + tx];
  __syncthreads();
  for (int i = ty; i < 32; i += 8)
    dst[(size_t)(c0 + i) * R + r0 + tx] = f2bf(t[tx][i]);
}

// ---------------- bf16 MFMA GEMM tile 128x128, BK=32 depth-3 (at-load) ------
template<int OBF16>
__device__ __forceinline__ void gemm_tile(
    const u16* __restrict__ A, const u16* __restrict__ BT,
    const float* __restrict__ bias, void* __restrict__ Cv,
    int K, int lda, int ldb, int ldc, int m0, int n0, int biasmode, bool slab,
    u16* As, u16* Bs) {
  const int tid = threadIdx.x;
  const int l = tid & 63, w = tid >> 6;
  const int r = l & 15, g = l >> 4;
  const int koff = slab ? (m0 / 384) * 768 : 0;
  const u16* Ap = A + ((size_t)m0 + w * 16 + r) * lda + g * 8;
  const u16* Bp = BT + ((size_t)n0 + w * 16 + r) * ldb + koff + g * 8;
  f32x4 acc[4][4] = {};
  const int wma = (w >> 1) * 4, wnb = (w & 1) * 4;
  const int nk = K >> 5;   // >= 12 for all call sites

  const u32 abase = lds_u32(As) + (u32)(wma * 1024 + l * 16);
  const u32 bbase = lds_u32(Bs) + (u32)(wnb * 1024 + l * 16);

  auto stage = [&](int kt, int buf) {
    const int o = buf * 4096;
    gload_lds16(Ap + kt,                    &As[o + (size_t)tid * 8]);
    gload_lds16(Ap + kt + (size_t)64 * lda, &As[o + 2048 + (size_t)tid * 8]);
    gload_lds16(Bp + kt,                    &Bs[o + (size_t)tid * 8]);
    gload_lds16(Bp + kt + (size_t)64 * ldb, &Bs[o + 2048 + (size_t)tid * 8]);
  };

  stage(0, 0);
  stage(32, 1);
  stage(64, 2);                     // 12 loads in flight
  int cur = 0;
  for (int t = 0; t < nk; ++t) {
    if (t + 2 < nk)      asm volatile("s_waitcnt vmcnt(8)" ::: "memory");
    else if (t + 1 < nk) asm volatile("s_waitcnt vmcnt(4)" ::: "memory");
    else                 asm volatile("s_waitcnt vmcnt(0)" ::: "memory");
    __builtin_amdgcn_s_barrier();   // tile t resident in buf cur (all waves)
    __builtin_amdgcn_sched_barrier(0);
    const u32 off = (u32)(cur * 8192);  // buffer stride 8KB
    short8 af[4], bfr[4];
    #pragma unroll
    for (int i = 0; i < 4; ++i) {
      asm volatile("ds_read_b128 %0, %1" : "=v"(af[i])  : "v"(abase + off + 1024u * i));
      asm volatile("ds_read_b128 %0, %1" : "=v"(bfr[i]) : "v"(bbase + off + 1024u * i));
    }
    asm volatile("s_waitcnt lgkmcnt(0)" ::: "memory");
    __builtin_amdgcn_sched_barrier(0);  // rule 18: nothing hoists above the wait
    __builtin_amdgcn_s_barrier();       // all waves' reads done -> buf cur free
    __builtin_amdgcn_sched_barrier(0);
    if (t + 3 < nk) stage((t + 3) << 5, cur);  // refill freed buffer, in flight
    #pragma unroll
    for (int mi = 0; mi < 4; ++mi)
      #pragma unroll
      for (int ni = 0; ni < 4; ++ni)
        acc[mi][ni] = __builtin_amdgcn_mfma_f32_16x16x32_bf16(af[mi], bfr[ni],
                                                              acc[mi][ni], 0, 0, 0);
    cur = (cur == 2) ? 0 : cur + 1;
  }

  const int row0 = m0 + (w >> 1) * 64, col0 = n0 + (w & 1) * 64;
  #pragma unroll
  for (int ni = 0; ni < 4; ++ni) {
    const int col = col0 + ni * 16 + r;
    const float bvc = (biasmode == 1) ? bias[col] : 0.f;
    #pragma unroll
    for (int mi = 0; mi < 4; ++mi)
      #pragma unroll
      for (int j = 0; j < 4; ++j) {
        const int row = row0 + mi * 16 + 4 * g + j;
        float bv = bvc;
        if (biasmode == 2) bv = bias[row];
        const float v = acc[mi][ni][j] + bv;
        if (OBF16) ((u16*)Cv)[(size_t)row * ldc + col] = f2bf(v);
        else       ((float*)Cv)[(size_t)row * ldc + col] = v;
      }
  }
}

// ---------------- bf16 MFMA GEMM tile 128x128, BK=64 (latency-bound) --------
template<int OBF16>
__device__ __forceinline__ void gemm_tile64(
    const u16* __restrict__ A, const u16* __restrict__ BT,
    const float* __restrict__ bias, void* __restrict__ Cv,
    int K, int lda, int ldb, int ldc, int m0, int n0, int biasmode, bool slab,
    u16* As, u16* Bs) {
  const int tid = threadIdx.x;
  const int l = tid & 63, w = tid >> 6;
  const int r = l & 15, g = l >> 4;
  const int koff = slab ? (m0 / 384) * 768 : 0;
  const u16* Ap = A + ((size_t)m0 + w * 16 + r) * lda + g * 8;
  const u16* Bp = BT + ((size_t)n0 + w * 16 + r) * ldb + koff + g * 8;
  f32x4 acc[4][4] = {};
  const int wma = (w >> 1) * 4, wnb = (w & 1) * 4;
  const int nk = K >> 6;   // BK=64; K in {384,768} -> nk in {6,12}

  const u32 abase = lds_u32(As) + (u32)(wma * 1024 + l * 16);
  const u32 bbase = lds_u32(Bs) + (u32)(wnb * 1024 + l * 16);

  // buffer = 16KB; khalf stride 8KB. Stage 8 chunks/thread per tile.
  auto stage = [&](int kt, int buf) {
    const int o = buf * 8192;                    // elems
    gload_lds16(Ap + kt,                         &As[o        + (size_t)tid * 8]);
    gload_lds16(Ap + kt      + (size_t)64 * lda, &As[o + 2048 + (size_t)tid * 8]);
    gload_lds16(Ap + kt + 32,                    &As[o + 4096 + (size_t)tid * 8]);
    gload_lds16(Ap + kt + 32 + (size_t)64 * lda, &As[o + 6144 + (size_t)tid * 8]);
    gload_lds16(Bp + kt,                         &Bs[o        + (size_t)tid * 8]);
    gload_lds16(Bp + kt      + (size_t)64 * ldb, &Bs[o + 2048 + (size_t)tid * 8]);
    gload_lds16(Bp + kt + 32,                    &Bs[o + 4096 + (size_t)tid * 8]);
    gload_lds16(Bp + kt + 32 + (size_t)64 * ldb, &Bs[o + 6144 + (size_t)tid * 8]);
  };

  stage(0, 0);
  stage(64, 1);                     // 16 loads in flight
  int cur = 0;
  for (int t = 0; t < nk; ++t) {
    if (t + 1 < nk) asm volatile("s_waitcnt vmcnt(8)" ::: "memory");
    else            asm volatile("s_waitcnt vmcnt(0)" ::: "memory");
    __builtin_amdgcn_s_barrier();   // tile t resident in buf cur (all waves)
    __builtin_amdgcn_sched_barrier(0);
    const u32 off = (u32)cur << 14; // cur * 16384 bytes
    short8 a0[4], b0[4], a1[4], b1[4];
    #pragma unroll
    for (int i = 0; i < 4; ++i) {
      asm volatile("ds_read_b128 %0, %1" : "=v"(a0[i]) : "v"(abase + off + 1024u * i));
      asm volatile("ds_read_b128 %0, %1" : "=v"(b0[i]) : "v"(bbase + off + 1024u * i));
    }
    #pragma unroll
    for (int i = 0; i < 4; ++i) {
      asm volatile("ds_read_b128 %0, %1" : "=v"(a1[i]) : "v"(abase + off + 8192u + 1024u * i));
      asm volatile("ds_read_b128 %0, %1" : "=v"(b1[i]) : "v"(bbase + off + 8192u + 1024u * i));
    }
    asm volatile("s_waitcnt lgkmcnt(8)" ::: "memory");
    __builtin_amdgcn_sched_barrier(0);  // rule 18
    #pragma unroll
    for (int mi = 0; mi < 4; ++mi)
      #pragma unroll
      for (int ni = 0; ni < 4; ++ni)
        acc[mi][ni] = __builtin_amdgcn_mfma_f32_16x16x32_bf16(a0[mi], b0[ni],
                                                              acc[mi][ni], 0, 0, 0);
    asm volatile("s_waitcnt lgkmcnt(0)" ::: "memory");
    __builtin_amdgcn_sched_barrier(0);  // rule 18
    __builtin_amdgcn_s_barrier();       // all waves' reads done -> buf cur free
    __builtin_amdgcn_sched_barrier(0);
    if (t + 2 < nk) stage((t + 2) << 6, cur);  // refill freed buffer, in flight
    #pragma unroll
    for (int mi = 0; mi < 4; ++mi)
      #pragma unroll
      for (int ni = 0; ni < 4; ++ni)
        acc[mi][ni] = __builtin_amdgcn_mfma_f32_16x16x32_bf16(a1[mi], b1[ni],
                                                              acc[mi][ni], 0, 0, 0);
    cur ^= 1;
  }

  const int row0 = m0 + (w >> 1) * 64, col0 = n0 + (w & 1) * 64;
  #pragma unroll
  for (int ni = 0; ni < 4; ++ni) {
    const int col = col0 + ni * 16 + r;
    const float bvc = (biasmode == 1) ? bias[col] : 0.f;
    #pragma unroll
    for (int mi = 0; mi < 4; ++mi)
      #pragma unroll
      for (int j = 0; j < 4; ++j) {
        const int row = row0 + mi * 16 + 4 * g + j;
        float bv = bvc;
        if (biasmode == 2) bv = bias[row];
        const float v = acc[mi][ni][j] + bv;
        if (OBF16) ((u16*)Cv)[(size_t)row * ldc + col] = f2bf(v);
        else       ((float*)Cv)[(size_t)row * ldc + col] = v;
      }
  }
}

// FUSED prep2: blocks [0,54) WcT; [54,72) WbpT; [72,80) bc; [80,6224) x-cast.
__global__ __launch_bounds__(256, 2) void gemm_prep(
    const u16* __restrict__ PT, const u16* __restrict__ Wat,
    const u16* __restrict__ WprT, const u16* __restrict__ Wbk,
    const float* __restrict__ ba, const float* __restrict__ x,
    u16* __restrict__ WcT, u16* __restrict__ WbpT, float* __restrict__ bc,
    u16* __restrict__ x_bf) {
  __shared__ alignas(16) u16 As[16384], Bs[16384];
  const int t = blockIdx.x;
  if (t >= 80) {  // x fp32->bf16 cast (independent of the GEMM jobs)
    const int i = (t - 80) * 256 + threadIdx.x;
    const float4 v = ((const float4*)x)[i];
    ((ushort4*)x_bf)[i] = make_ushort4(f2bf(v.x), f2bf(v.y), f2bf(v.z), f2bf(v.w));
    return;
  }
  if (t < 54) {
    gemm_tile64<1>(PT, Wat, nullptr, WcT, 768, 768, 2304, 768,
                   (t % 9) * 128, (t / 9) * 128, 0, true, As, Bs);
  } else if (t < 72) {
    const int t2 = t - 54;
    gemm_tile64<1>(WprT, Wbk, nullptr, WbpT, 768, 768, 768, 384,
                   (t2 % 6) * 128, (t2 / 6) * 128, 0, false, As, Bs);
  } else {
    const int c = (t - 72) * 144 + threadIdx.x;
    if (threadIdx.x < 144 && c < 1152) {
      const int slab = c / 384;
      const float* bs = ba + slab * 768;
      const u16* row = PT + (size_t)c * 768;
      float s = 0.f;
      for (int jj = 0; jj < 96; ++jj) {
        const short8 v = *(const short8*)&row[jj * 8];
        #pragma unroll
        for (int e = 0; e < 8; ++e)
          s = fmaf(bs[jj * 8 + e], b2f((u16)v[e]), s);
      }
      bc[c] = s;
    }
  }
}

// main GEMMs, XCD-chunked: logical w groups the 9 jobs reading one 128-token
// x_bf strip (6 QK col-panels + 3 VT row-panels); xcd = t%8 round-robin.
__global__ __launch_bounds__(256, 3) void gemm_qkvt(
    const u16* __restrict__ x_bf, const u16* __restrict__ WcT,
    const float* __restrict__ bc, u16* __restrict__ QKbuf, u16* __restrict__ VTbuf) {
  __shared__ alignas(16) u16 As[12288], Bs[12288];
  const int t = blockIdx.x;                 // 576 = 8 xcd * 72
  const int w = (t & 7) * 72 + (t >> 3);    // XCD-chunked logical id
  const int s = w / 9, j = w % 9;           // token strip, sub-job
  if (j < 6) {
    gemm_tile<1>(x_bf, WcT, bc, QKbuf, 768, 768, 768, 768,
                 s * 128, j * 128, 1, false, As, Bs);
  } else {
    gemm_tile<1>(WcT + (size_t)768 * 768, x_bf, bc + 768, VTbuf, 768, 768, 768, VLD,
                 (j - 6) * 128, s * 128, 2, false, As, Bs);
  }
}

__global__ __launch_bounds__(256, 2) void gemm_out(
    const u16* __restrict__ ctx, const u16* __restrict__ WbpT,
    const float* __restrict__ bp, float* __restrict__ out) {
  __shared__ alignas(16) u16 As[16384], Bs[16384];
  const int t = blockIdx.x;                 // 384 = 8 xcd * 48
  const int w = (t & 7) * 48 + (t >> 3);    // XCD-chunked logical id
  gemm_tile64<0>(ctx, WbpT, bp, out, 384, 384, 384, 768,
                 (w / 6) * 128, (w % 6) * 128, 1, false, As, Bs);
}

// ---------------- causal flash attention, KVBLK=128, 4-wave blocks ----------
// grid: 768 blocks x 256 thr (heavy chunks first, global order — R1-proven).
// Block = 128 q-rows of one (b,h); wave w owns rows [cc*128 + w*32, +32).
// Per barrier-step: stage a 128-k K tile (global_load_lds, 2 chunks/thread)
// and a 32x128 V tile (reg->LDS, 2 uint4/thread, issue-early/write-late T14);
// compute as TWO serial 64-k halves (same reg footprint as KVBLK=64).
__global__ __launch_bounds__(256, 4) void attn_kernel(
    const u16* __restrict__ QK, const u16* __restrict__ VT,
    u16* __restrict__ ctx) {
  __shared__ alignas(16) u16 Ks[2][4096];       // 8KB per buffer (128k x 32hd)
  __shared__ alignas(16) u16 Vs[2][32 * 136];   // 8.5KB per buffer (padded rows)
  const int tid = threadIdx.x;
  const int w = tid >> 6, l = tid & 63;
  const int r = l & 15, g = l >> 4;
  const int idx = blockIdx.x;
  const int cc = 15 - idx / 48;                // q-chunk (128 rows), heavy first
  const int bh = idx % 48;
  const int b = bh / 12, h = bh % 12;
  const size_t tok0 = (size_t)b * 2048;
  const int q0 = cc * 128 + w * 32;            // this wave's q-strip base
  const u16* Qb = QK + (tok0 + q0) * 768 + h * 32;
  const u16* Kb = QK + tok0 * 768 + 384 + h * 32;
  const u16* Vb = VT + (size_t)(h * 32) * VLD + b * 2048;
  const float scale2 = 0.25500526474f;         // (1/sqrt(32))*log2(e)
  const float THR = 8.0f;                      // defer-max threshold (T13)
  const f32x4 fz = {0.f, 0.f, 0.f, 0.f};

  short8 qf[2];
  qf[0] = *(const short8*)&Qb[(size_t)r * 768 + 8 * g];
  qf[1] = *(const short8*)&Qb[(size_t)(16 + r) * 768 + 8 * g];

  float mrun[2] = {-3.0e38f, -3.0e38f};
  float lpart[2] = {0.f, 0.f};                 // per-lane partial row sums
  f32x4 o[2][2] = {};                          // o[di][mi]: d=16di+4g+jj, q=16mi+r
  const int nt = cc + 1;                       // 128-k tiles in this chunk

  // staging roles (fixed per thread; all 256 threads do K and V)
  const int krow = ((tid >> 6) << 4) + (tid & 15);   // K chunk row (0..63)
  const int kcol = ((tid >> 4) & 3) * 8;             // K chunk col
  const int vd   = tid >> 3;                          // V row d (0..31)
  const int vkc  = (tid & 7) * 8;                     // V col chunk (0..56)

  uint4 vreg0, vreg1;
  auto stageK = [&](int t, int buf) {
    gload_lds16(&Kb[(size_t)(t * 128 + krow) * 768 + kcol],      &Ks[buf][(size_t)tid * 8]);
    gload_lds16(&Kb[(size_t)(t * 128 + 64 + krow) * 768 + kcol], &Ks[buf][(size_t)(tid + 256) * 8]);
  };
  auto loadV = [&](int t) {
    vreg0 = *(const uint4*)&Vb[(size_t)vd * VLD + t * 128 + vkc];
    vreg1 = *(const uint4*)&Vb[(size_t)vd * VLD + t * 128 + 64 + vkc];
  };
  auto writeV = [&](int buf) {
    *(uint4*)&Vs[buf][vd * 136 + vkc]      = vreg0;
    *(uint4*)&Vs[buf][vd * 136 + 64 + vkc] = vreg1;
  };

  loadV(0); stageK(0, 0); writeV(0);
  __syncthreads();
  int cur = 0;
  for (int t = 0; t < nt; ++t) {
    const bool pf = (t + 1 < nt);
    if (pf) { loadV(t + 1); stageK(t + 1, cur ^ 1); }  // issue next tile early
    #pragma unroll
    for (int hh = 0; hh < 2; ++hh) {
      const int k0 = t * 128 + hh * 64;
      if (k0 > q0 + 31) continue;              // wave fully above this half
      // K fragments: lane holds K[k=k0+16kj+r][hd=8g..]
      short8 kf[4];
      #pragma unroll
      for (int kj = 0; kj < 4; ++kj)
        kf[kj] = *(const short8*)&Ks[cur][(hh * 256 + kj * 64 + l) * 8];
      // V^T fragments: lane holds VT[d=16di+r][k=k0+16kj+4g..+3]
      bf16x4 vf[2][4];
      #pragma unroll
      for (int di = 0; di < 2; ++di)
        #pragma unroll
        for (int kj = 0; kj < 4; ++kj)
          vf[di][kj] = *(const bf16x4*)&Vs[cur][(16 * di + r) * 136 + hh * 64 + kj * 16 + 4 * g];

      // S^T = K Q^T : lane holds S[k=k0+16kj+4g+jj][q=16mi+r]  (raw)
      f32x4 s[2][4];
      __builtin_amdgcn_s_setprio(1);
      #pragma unroll
      for (int kj = 0; kj < 4; ++kj)
        #pragma unroll
        for (int mi = 0; mi < 2; ++mi)
          s[mi][kj] = __builtin_amdgcn_mfma_f32_16x16x32_bf16(kf[kj], qf[mi], fz, 0, 0, 0);
      __builtin_amdgcn_s_setprio(0);

      if (t == nt - 1) {  // only the diagonal tile needs masking
        #pragma unroll
        for (int mi = 0; mi < 2; ++mi) {
          const int qq = q0 + mi * 16 + r;
          #pragma unroll
          for (int kj = 0; kj < 4; ++kj)
            #pragma unroll
            for (int jj = 0; jj < 4; ++jj) {
              const int kk = k0 + kj * 16 + 4 * g + jj;
              if (kk > qq) s[mi][kj][jj] = -3.0e38f;
            }
        }
      }

      #pragma unroll
      for (int mi = 0; mi < 2; ++mi) {
        const float a0 = fmaxf(fmaxf(s[mi][0][0], s[mi][0][1]), fmaxf(s[mi][0][2], s[mi][0][3]));
        const float a1 = fmaxf(fmaxf(s[mi][1][0], s[mi][1][1]), fmaxf(s[mi][1][2], s[mi][1][3]));
        const float a2 = fmaxf(fmaxf(s[mi][2][0], s[mi][2][1]), fmaxf(s[mi][2][2], s[mi][2][3]));
        const float a3 = fmaxf(fmaxf(s[mi][3][0], s[mi][3][1]), fmaxf(s[mi][3][2], s[mi][3][3]));
        const float lmxs = fmaxf(fmaxf(a0, a1), fmaxf(a2, a3)) * scale2;
        if (__any(lmxs > mrun[mi] + THR)) {    // rare: reduce + per-lane rescale
          float mx = lmxs;
          mx = fmaxf(mx, __shfl_xor(mx, 16));
          mx = fmaxf(mx, __shfl_xor(mx, 32));
          const float mnew = fmaxf(mrun[mi], mx);
          const float al = exp2v(mrun[mi] - mnew);
          mrun[mi] = mnew;
          lpart[mi] *= al;
          o[0][mi] *= al;                      // q lane-indexed: plain multiply
          o[1][mi] *= al;
        }
        #pragma unroll
        for (int kj = 0; kj < 4; ++kj)
          #pragma unroll
          for (int jj = 0; jj < 4; ++jj) {
            const float pv = exp2v(fmaf(s[mi][kj][jj], scale2, -mrun[mi]));
            s[mi][kj][jj] = pv;
            lpart[mi] += pv;
          }
      }

      // PV in-register: O^T[d][q] += V^T[d][k] * P^T[k][q]
      __builtin_amdgcn_s_setprio(1);
      #pragma unroll
      for (int kj = 0; kj < 4; ++kj) {
        const bf16x4 pf0 = pack4(s[0][kj]);
        const bf16x4 pf1 = pack4(s[1][kj]);
        #pragma unroll
        for (int di = 0; di < 2; ++di) {
          o[di][0] = mfma16bf(vf[di][kj], pf0, o[di][0]);
          o[di][1] = mfma16bf(vf[di][kj], pf1, o[di][1]);
        }
      }
      __builtin_amdgcn_s_setprio(0);
    }
    if (pf) writeV(cur ^ 1);                   // land V after compute (T14)
    __syncthreads();
    cur ^= 1;
  }

  // epilogue: per-wave l reduction (2 shfl) + direct store (no merge)
  #pragma unroll
  for (int mi = 0; mi < 2; ++mi) {
    float lr = lpart[mi];
    lr += __shfl_xor(lr, 16);
    lr += __shfl_xor(lr, 32);
    const float li = 1.0f / lr;
    const size_t row = tok0 + q0 + mi * 16 + r;
    #pragma unroll
    for (int di = 0; di < 2; ++di) {
      const u32 d0 = cvtpk_bf16(o[di][mi][0] * li, o[di][mi][1] * li);
      const u32 d1 = cvtpk_bf16(o[di][mi][2] * li, o[di][mi][3] * li);
      *(uint2*)&ctx[row * 384 + h * 32 + di * 16 + 4 * g] = make_uint2(d0, d1);
    }
  }
}

// ---------------------------------------------------------------------------
extern "C" void kernel_launch(void* const* d_in, const int* in_sizes, int n_in,
                              void* d_out, int out_size, void* d_ws, size_t ws_size,
                              hipStream_t stream) {
  const float* x      = (const float*)d_in[0];
  const float* W_attn = (const float*)d_in[1];
  const float* b_attn = (const float*)d_in[2];
  const float* P_q    = (const float*)d_in[3];
  const float* P_k    = (const float*)d_in[4];
  const float* P_v    = (const float*)d_in[5];
  const float* W_back = (const float*)d_in[6];
  const float* W_proj = (const float*)d_in[7];
  const float* b_proj = (const float*)d_in[8];

  char* ws = (char*)d_ws;
  u16*   x_bf   = (u16*)(ws);               // 8192x768 bf16
  u16*   ctx    = (u16*)(ws);               // 8192x384, aliases dead x_bf
  u16*   Wat_bf = (u16*)(ws + 12582912);    // 768x2304
  u16*   PT     = (u16*)(ws + 16121856);    // 1152x768
  u16*   Wbk_bf = (u16*)(ws + 17891328);    // 384x768
  u16*   WprT   = (u16*)(ws + 18481152);    // 768x768
  u16*   WcT    = (u16*)(ws + 19660800);    // 1152x768
  u16*   WbpT   = (u16*)(ws + 21430272);    // 768x384
  float* bc     = (float*)(ws + 22020096);  // 1152
  u16*   QKbuf  = (u16*)d_out;                          // 8192x768 (dead before gemm_out)
  u16*   VTbuf  = (u16*)((char*)d_out + 12582912);      // 384xVLD (dead before gemm_out)
  float* out    = (float*)d_out;

  prep_w<<<3456, 256, 0, stream>>>(W_attn, W_back, P_q, P_k, P_v, W_proj,
                                   Wat_bf, Wbk_bf, PT, WprT);
  gemm_prep<<<6224, 256, 0, stream>>>(PT, Wat_bf, WprT, Wbk_bf, b_attn, x,
                                      WcT, WbpT, bc, x_bf);
  gemm_qkvt<<<576, 256, 0, stream>>>(x_bf, WcT, bc, QKbuf, VTbuf);
  attn_kernel<<<768, 256, 0, stream>>>(QKbuf, VTbuf, ctx);
  gemm_out<<<384, 256, 0, stream>>>(ctx, WbpT, b_proj, out);
}